// Round 16
// baseline (266.368 us; speedup 1.0000x reference)
//
#include <hip/hip_runtime.h>

typedef __attribute__((ext_vector_type(8))) short short8;
typedef __attribute__((ext_vector_type(4))) float f32x4;
typedef __attribute__((ext_vector_type(4))) int i32x4;

constexpr int TT = 2048, CC = 2048, HQ = 16, GG = 4, DD = 128, IC = 8192;

__device__ __forceinline__ ushort f2b(float f) {
  union { float f; unsigned u; } v; v.f = f;
  unsigned r = v.u + 0x7fffu + ((v.u >> 16) & 1u);
  return (ushort)(r >> 16);
}
__device__ __forceinline__ float b2f(ushort u) {
  union { unsigned u; float f; } v; v.u = ((unsigned)u) << 16; return v.f;
}
__device__ __forceinline__ char q8(float eff, float r) {
  float q = rintf(eff * r);
  q = fminf(fmaxf(q, -127.f), 127.f);
  return (char)(int)q;
}
__device__ __forceinline__ unsigned cvt_pk_bf16(float a, float b) {
  unsigned r;
  asm("v_cvt_pk_bf16_f32 %0, %1, %2" : "=v"(r) : "v"(a), "v"(b));
  return r;
}

__device__ __forceinline__ void gload16(const void* g, void* l) {
  __builtin_amdgcn_global_load_lds(
      (const __attribute__((address_space(1))) void*)g,
      (__attribute__((address_space(3))) void*)l, 16, 0, 0);
}

#define BAR()    __builtin_amdgcn_s_barrier()
#define PRIO1()  __builtin_amdgcn_s_setprio(1)
#define PRIO0()  __builtin_amdgcn_s_setprio(0)

// ====== 256x256 i8 GEMM, R7 pipeline clone: C[M,N] = (A{0,1} @ Bq^T) * s[n] ======
template<int EPI>
__global__ __launch_bounds__(512, 2)
void gemm_i8(const char* __restrict__ A, const char* __restrict__ B,
             void* __restrict__ C0, const float* __restrict__ s,
             const float* __restrict__ beta, int M, int N, int K, int kc)
{
  __shared__ alignas(16) char lds[131072];
  const int tid = threadIdx.x;
  const int l = tid & 63, w = tid >> 6;
  const int fl = l & 15, fh = l >> 4;
  const int wrm = w >> 2, wcn = w & 3;
  const int m0 = blockIdx.y * 256, n0 = blockIdx.x * 256;
  const int kBeg = blockIdx.z * kc;
  const int kEnd = (kBeg + kc < K) ? kBeg + kc : K;
  const int nt = (kEnd - kBeg) >> 7;

  i32x4 acc[8][4] = {};

  const int srow = tid >> 3;
  const int scol = ((tid & 7) ^ (srow & 7)) * 16;
  const char* Ag = A + (size_t)(m0 + srow) * K + kBeg + scol;
  const char* Bg = B + (size_t)(n0 + srow) * K + kBeg + scol;

  auto stage_half = [&](int tile, int h) {
    const char* base = (h < 2) ? Ag : Bg;
    const int half = h & 1;
    const char* g = base + (size_t)(half * 128) * K + tile * 128;
    char* d = lds + (tile & 1) * 65536 + ((h < 2) ? 0 : 32768) + half * 16384 + tid * 16;
    gload16(g, d);
    gload16(g + (size_t)64 * K, d + 8192);
  };

  auto readA = [&](i32x4 (&dst)[4][2], int buf, int mofs) {
#pragma unroll
    for (int mf = 0; mf < 4; ++mf)
#pragma unroll
      for (int ks = 0; ks < 2; ++ks) {
        int row = wrm * 128 + (mofs + mf) * 16 + fl;
        dst[mf][ks] = *(const i32x4*)(lds + buf * 65536 + row * 128 +
                                      (((ks * 4 + fh) ^ (row & 7)) * 16));
      }
  };
  auto readB = [&](i32x4 (&dst)[2][2], int buf, int nofs) {
#pragma unroll
    for (int nf = 0; nf < 2; ++nf)
#pragma unroll
      for (int ks = 0; ks < 2; ++ks) {
        int row = wcn * 64 + (nofs + nf) * 16 + fl;
        dst[nf][ks] = *(const i32x4*)(lds + buf * 65536 + 32768 + row * 128 +
                                      (((ks * 4 + fh) ^ (row & 7)) * 16));
      }
  };
  auto mmQ = [&](i32x4 (&a)[4][2], i32x4 (&b)[2][2], int mo, int no) {
    PRIO1();
#pragma unroll
    for (int mf = 0; mf < 4; ++mf)
#pragma unroll
      for (int nf = 0; nf < 2; ++nf)
#pragma unroll
        for (int ks = 0; ks < 2; ++ks)
          acc[mo + mf][no + nf] = __builtin_amdgcn_mfma_i32_16x16x64_i8(
              a[mf][ks], b[nf][ks], acc[mo + mf][no + nf], 0, 0, 0);
    PRIO0();
  };

  stage_half(0, 0); stage_half(0, 1); stage_half(0, 2); stage_half(0, 3);
  if (nt > 1) {
    stage_half(1, 2); stage_half(1, 3);
    asm volatile("s_waitcnt vmcnt(4)" ::: "memory");
  } else {
    asm volatile("s_waitcnt vmcnt(0)" ::: "memory");
  }
  BAR();

  for (int t = 0; t < nt; ++t) {
    const int buf = t & 1;
    i32x4 A0[4][2], A1[4][2], B0[2][2], B1[2][2];

    readA(A0, buf, 0);
    readB(B0, buf, 0);
    if (t + 1 < nt) stage_half(t + 1, 0);
    BAR();
    mmQ(A0, B0, 0, 0);

    readB(B1, buf, 2);
    if (t + 1 < nt) stage_half(t + 1, 1);
    BAR();
    mmQ(A0, B1, 0, 2);

    readA(A1, buf, 4);
    BAR();
    mmQ(A1, B0, 4, 0);

    if (t + 2 < nt) { stage_half(t + 2, 2); stage_half(t + 2, 3); }
    if (t <= nt - 3) asm volatile("s_waitcnt vmcnt(4)" ::: "memory");
    else             asm volatile("s_waitcnt vmcnt(0)" ::: "memory");
    BAR();
    mmQ(A1, B1, 4, 2);
  }

  const int orow0 = m0 + wrm * 128 + fh * 4;
  const int ocol0 = n0 + wcn * 64 + fl;
#pragma unroll
  for (int mf = 0; mf < 8; ++mf) {
#pragma unroll
    for (int nf = 0; nf < 4; ++nf) {
      const int c = ocol0 + nf * 16;
      const float sc = s[c];
#pragma unroll
      for (int j = 0; j < 4; ++j) {
        const int r = orow0 + mf * 16 + j;
        const size_t o = (size_t)r * N + c;
        float v = (float)acc[mf][nf][j] * sc;
        if constexpr (EPI == 1) {
          ((char*)C0)[o] = (v - beta[c] > 0.f) ? (char)1 : (char)0;
        } else {
          ((ushort*)C0 + (size_t)blockIdx.z * M * N)[o] = f2b(v);
        }
      }
    }
  }
}

// ---------------- split-K reduce: bf16 partial planes ----------------
template<int NS, int MODE>
__global__ void reduce_kernel(const ushort* p0, const ushort* p1, const ushort* p2, const ushort* p3,
                              const float* resid, float* outf, char* outb,
                              const float* beta, int n4, int cols)
{
  const ushort* ps[4] = {p0, p1, p2, p3};
  for (int i = blockIdx.x * blockDim.x + threadIdx.x; i < n4; i += gridDim.x * blockDim.x) {
    float4 s = ((const float4*)resid)[i];
#pragma unroll
    for (int z = 0; z < NS; ++z) {
      ushort4 q = ((const ushort4*)ps[z])[i];
      s.x += b2f(q.x); s.y += b2f(q.y); s.z += b2f(q.z); s.w += b2f(q.w);
    }
    ((float4*)outf)[i] = s;
    if constexpr (MODE == 1) {
      int c = (i * 4) & (cols - 1);
      char4 r;
      r.x = (s.x - beta[c] > 0.f) ? 1 : 0;
      r.y = (s.y - beta[c + 1] > 0.f) ? 1 : 0;
      r.z = (s.z - beta[c + 2] > 0.f) ? 1 : 0;
      r.w = (s.w - beta[c + 3] > 0.f) ? 1 : 0;
      ((char4*)outb)[i] = r;
    }
  }
}

// ---- attn v4: Q in regs, single-buffered K/V, swapped-QK^T P phase (cvt_pk + b64 writes) ----
__global__ __launch_bounds__(256, 4)
void attn_kernel(const ushort* __restrict__ qb, const ushort* __restrict__ kb,
                 const ushort* __restrict__ vt, char* __restrict__ hy,
                 const float* __restrict__ obeta)
{
  __shared__ alignas(16) ushort Ks[64 * 128];   // [s][d] swizzled, 16KB
  __shared__ alignas(16) ushort Vs[128 * 64];   // [d][s] swizzled, 16KB
  __shared__ alignas(16) ushort Ps[64 * 64];    // [q][s] swizzled, 8KB
  const int bx = blockIdx.x;
  const int h = blockIdx.y;
  const int qi = (h & 8) ? bx : (31 - bx);
  const int g = h >> 2;
  const int q0 = qi * 64;
  const int tid = threadIdx.x;
  const int w = tid >> 6, l = tid & 63;
  const int fl = l & 15, fh = l >> 4;

  auto stageK = [&](int s0t) {
#pragma unroll
    for (int i = 0; i < 4; ++i) {
      int row = w * 16 + i * 4 + (l >> 4);
      int c16 = (l & 15) ^ (row & 7);
      gload16(kb + (size_t)g * TT * DD + (size_t)(s0t + row) * DD + c16 * 8,
              (char*)Ks + (w << 12) + (i << 10) + (l << 4));
    }
  };
  auto stageV = [&](int s0t) {
#pragma unroll
    for (int i = 0; i < 4; ++i) {
      int d = w * 32 + i * 8 + (l >> 3);
      int c16 = (l & 7) ^ (d & 7);
      gload16(vt + (size_t)g * DD * TT + (size_t)d * TT + s0t + c16 * 8,
              (char*)Vs + (w << 12) + (i << 10) + (l << 4));
    }
  };

  // Q fragments -> registers
  short8 qf[4];
  {
    const ushort* qp = qb + (size_t)h * TT * DD + (size_t)(q0 + w * 16 + fl) * DD + fh * 8;
#pragma unroll
    for (int ks = 0; ks < 4; ++ks) qf[ks] = *(const short8*)(qp + ks * 32);
  }

  const int prow = w * 16 + fl;       // this lane's q-row (within block)
  const int qg = q0 + prow;           // global q index
  f32x4 oacc[8] = {};

  for (int s0 = 0; s0 <= q0; s0 += 64) {
    stageK(s0); stageV(s0);
    asm volatile("s_waitcnt vmcnt(0)" ::: "memory");
    BAR();

    // S^T = K Q^T : lane holds S[s0+n*16+fh*4+j][qg] for j=0..3, n=0..3
    f32x4 sacc[4] = {};
#pragma unroll
    for (int ks = 0; ks < 4; ++ks) {
#pragma unroll
      for (int n = 0; n < 4; ++n) {
        int krow = n * 16 + fl;
        int slotB = (ks * 4 + fh) ^ (krow & 7);
        short8 kf = *(const short8*)((char*)Ks + krow * 256 + slotB * 16);
        sacc[n] = __builtin_amdgcn_mfma_f32_16x16x32_bf16(kf, qf[ks], sacc[n], 0, 0, 0);
      }
    }

    // P row is lane-local: relu(/mask) -> pack pairs -> 4x ds_write_b64
    const bool diag = (s0 == q0);
#pragma unroll
    for (int n = 0; n < 4; ++n) {
      float p[4];
#pragma unroll
      for (int j = 0; j < 4; ++j) {
        float v = sacc[n][j] * 0.0078125f;
        v = fmaxf(v, 0.f);
        if (diag) {
          int sg = s0 + n * 16 + fh * 4 + j;
          if (sg > qg) v = 0.f;
        }
        p[j] = v;
      }
      unsigned lo = cvt_pk_bf16(p[0], p[1]);
      unsigned hi = cvt_pk_bf16(p[2], p[3]);
      int slot = ((n * 2 + (fh >> 1)) ^ (prow & 7));
      char* addr = (char*)Ps + prow * 128 + slot * 16 + ((fh & 1) << 3);
      uint2 val; val.x = lo; val.y = hi;
      *(uint2*)addr = val;
    }

    // O += P V
#pragma unroll
    for (int ks = 0; ks < 2; ++ks) {
      int slotA = (ks * 4 + fh) ^ (prow & 7);
      short8 pa = *(const short8*)((char*)Ps + prow * 128 + slotA * 16);
#pragma unroll
      for (int n = 0; n < 8; ++n) {
        int vrow = n * 16 + fl;
        int slotB = (ks * 4 + fh) ^ (vrow & 7);
        short8 vb = *(const short8*)((char*)Vs + vrow * 128 + slotB * 16);
        oacc[n] = __builtin_amdgcn_mfma_f32_16x16x32_bf16(pa, vb, oacc[n], 0, 0, 0);
      }
    }

    BAR();   // all reads of Ks/Vs done before next iteration's stage
  }

#pragma unroll
  for (int n = 0; n < 8; ++n) {
    const int c = h * DD + n * 16 + fl;
    const float be = obeta[c];
#pragma unroll
    for (int j = 0; j < 4; ++j) {
      const int tq = q0 + w * 16 + fh * 4 + j;
      float v = oacc[n][j];
      hy[(size_t)tq * CC + c] = (v - be > 0.f) ? (char)1 : (char)0;
    }
  }
}

// ---------- rope + hv on q/k, transpose+cast v ; split across blockIdx.z ----------
__global__ __launch_bounds__(256)
void rope_hv_kernel(const ushort* __restrict__ qp0, const ushort* __restrict__ qp1,
                    const float* __restrict__ cs, const float* __restrict__ sn,
                    const float* __restrict__ qalpha, const float* __restrict__ qbeta,
                    const float* __restrict__ kalpha, const float* __restrict__ kbeta,
                    ushort* __restrict__ qb, ushort* __restrict__ kb,
                    ushort* __restrict__ vt)
{
  __shared__ ushort Vsh[64][129];
  const int t0 = blockIdx.x * 64, g = blockIdx.y, job = blockIdx.z;
  const int tid = threadIdx.x;
  if (job < 5) {
    const int hh = job;
    const float* alpha = (hh < 4) ? qalpha : kalpha;
    const float* beta = (hh < 4) ? qbeta : kbeta;
    const int hoff = (hh < 4) ? hh * 128 : 512;
    for (int it = 0; it < 16; ++it) {
      int idx = it * 256 + tid;
      int tr = idx >> 6, dd = idx & 63;
      size_t base = (size_t)(t0 + tr) * 3072 + g * 768 + hoff;
      float x1 = b2f(qp0[base + dd]) + b2f(qp1[base + dd]);
      float x2 = b2f(qp0[base + 64 + dd]) + b2f(qp1[base + 64 + dd]);
      float c = cs[(size_t)(t0 + tr) * 64 + dd];
      float s = sn[(size_t)(t0 + tr) * 64 + dd];
      float o1 = x1 * c - x2 * s, o2 = x1 * s + x2 * c;
      ushort b1 = (o1 - beta[dd] > 0.f) ? f2b(alpha[dd]) : (ushort)0;
      ushort b2 = (o2 - beta[64 + dd] > 0.f) ? f2b(alpha[64 + dd]) : (ushort)0;
      if (hh < 4) {
        size_t o = ((size_t)(g * 4 + hh) * TT + t0 + tr) * DD;
        qb[o + dd] = b1;
        qb[o + 64 + dd] = b2;
      } else {
        size_t o = ((size_t)g * TT + t0 + tr) * DD;
        kb[o + dd] = b1;
        kb[o + 64 + dd] = b2;
      }
    }
  } else {
    for (int it = 0; it < 32; ++it) {
      int idx = it * 256 + tid;
      int tr = idx >> 7, d = idx & 127;
      size_t src = (size_t)(t0 + tr) * 3072 + g * 768 + 640 + d;
      Vsh[tr][d] = f2b(b2f(qp0[src]) + b2f(qp1[src]));
    }
    __syncthreads();
    for (int it = 0; it < 32; ++it) {
      int idx = it * 256 + tid;
      int d = idx >> 6, tl = idx & 63;
      vt[((size_t)g * DD + d) * TT + t0 + tl] = Vsh[tl][d];
    }
  }
}

// ======== single-pass fused rowmax + i8 quantization + h_in ========
// launch_bounds(256,4): 128 VGPRs/wave so the ef[8] row tile stays RESIDENT in
// registers (at (256,8) the allocator squeezed to 32 VGPR and re-loaded the row
// in the store pass -> 2.5 TB/s plateau).
__global__ __launch_bounds__(256, 4)
void quant_fused(const float* __restrict__ attn_w, char* __restrict__ attn_q,
                 const float* __restrict__ fc_w, char* __restrict__ fc_q,
                 const float* __restrict__ proj_w, char* __restrict__ proj_q,
                 const float* __restrict__ mlp_w, char* __restrict__ mlp_q,
                 const float* __restrict__ inA, const float* __restrict__ a1A,
                 const float* __restrict__ p_iva, const float* __restrict__ p_muiva,
                 const float* __restrict__ m_iva, const float* __restrict__ m_muiva,
                 float* __restrict__ s_all,
                 const float* __restrict__ x, const float* __restrict__ ib,
                 char* __restrict__ h_in)
{
  __shared__ float wmax[4];
  const int bx = blockIdx.x;
  const int tid = threadIdx.x;
  const int wv = tid >> 6, lane = tid & 63;

  if (bx < 3328) {
    const float* W; char* Q; const float4* A4;
    const float4* MUIVA4 = nullptr;
    int row, sofs;
    if (bx < 768)       { W = attn_w; Q = attn_q; A4 = (const float4*)inA;   row = bx * 4 + wv;          sofs = 0; }
    else if (bx < 2816) { W = fc_w;   Q = fc_q;   A4 = (const float4*)a1A;   row = (bx - 768) * 4 + wv;  sofs = 3072; }
    else                { W = proj_w; Q = proj_q; A4 = (const float4*)p_iva; row = (bx - 2816) * 4 + wv; sofs = 11264;
                          MUIVA4 = (const float4*)p_muiva; }
    const float4* src = (const float4*)(W + (size_t)row * 2048);
    char4* dst = (char4*)(Q + (size_t)row * 2048);
    float4 ef[8];
    float m = 0.f;
#pragma unroll
    for (int it = 0; it < 8; ++it) {
      int i = it * 64 + lane;
      float4 v = src[i];
      float4 a = A4[i];
      float4 e;
      if (MUIVA4) {
        float4 mv = MUIVA4[i];
        e.x = fmaf(v.x, a.x, -mv.x);
        e.y = fmaf(v.y, a.y, -mv.y);
        e.z = fmaf(v.z, a.z, -mv.z);
        e.w = fmaf(v.w, a.w, -mv.w);
      } else {
        e.x = v.x * a.x; e.y = v.y * a.y; e.z = v.z * a.z; e.w = v.w * a.w;
      }
      ef[it] = e;
      m = fmaxf(m, fmaxf(fmaxf(fabsf(e.x), fabsf(e.y)), fmaxf(fabsf(e.z), fabsf(e.w))));
    }
    for (int mask = 32; mask; mask >>= 1) m = fmaxf(m, __shfl_xor(m, mask));
    if (lane == 0) s_all[sofs + row] = m * (1.f / 127.f);
    const float r = (m > 0.f) ? 127.f / m : 0.f;
#pragma unroll
    for (int it = 0; it < 8; ++it) {
      int i = it * 64 + lane;
      char4 q;
      q.x = q8(ef[it].x, r); q.y = q8(ef[it].y, r);
      q.z = q8(ef[it].z, r); q.w = q8(ef[it].w, r);
      dst[i] = q;
    }
  } else if (bx < 5376) {
    const int row = bx - 3328;
    const float4* src = (const float4*)(mlp_w + (size_t)row * 8192);
    const float4* A4 = (const float4*)m_iva;
    const float4* MUIVA4 = (const float4*)m_muiva;
    char4* dst = (char4*)(mlp_q + (size_t)row * 8192);
    float4 ef[8];
    float m = 0.f;
#pragma unroll
    for (int it = 0; it < 8; ++it) {
      int i = wv * 512 + it * 64 + lane;
      float4 v = src[i];
      float4 a = A4[i], mv = MUIVA4[i];
      float4 e;
      e.x = fmaf(v.x, a.x, -mv.x);
      e.y = fmaf(v.y, a.y, -mv.y);
      e.z = fmaf(v.z, a.z, -mv.z);
      e.w = fmaf(v.w, a.w, -mv.w);
      ef[it] = e;
      m = fmaxf(m, fmaxf(fmaxf(fabsf(e.x), fabsf(e.y)), fmaxf(fabsf(e.z), fabsf(e.w))));
    }
    for (int mask = 32; mask; mask >>= 1) m = fmaxf(m, __shfl_xor(m, mask));
    if (lane == 0) wmax[wv] = m;
    __syncthreads();
    m = fmaxf(fmaxf(wmax[0], wmax[1]), fmaxf(wmax[2], wmax[3]));
    if (tid == 0) s_all[13312 + row] = m * (1.f / 127.f);
    const float r = (m > 0.f) ? 127.f / m : 0.f;
#pragma unroll
    for (int it = 0; it < 8; ++it) {
      int i = wv * 512 + it * 64 + lane;
      char4 q;
      q.x = q8(ef[it].x, r); q.y = q8(ef[it].y, r);
      q.z = q8(ef[it].z, r); q.w = q8(ef[it].w, r);
      dst[i] = q;
    }
  } else {
    const int blk = bx - 5376;
    const int stride = 512 * 256;
    const float4* ib4 = (const float4*)ib;
    for (int i = blk * 256 + tid; i < 2048 * 2048 / 4; i += stride) {
      float4 v = ((const float4*)x)[i];
      float4 b = ib4[i & 511];
      char4 q;
      q.x = (v.x - b.x > 0.f) ? 1 : 0;
      q.y = (v.y - b.y > 0.f) ? 1 : 0;
      q.z = (v.z - b.z > 0.f) ? 1 : 0;
      q.w = (v.w - b.w > 0.f) ? 1 : 0;
      ((char4*)h_in)[i] = q;
    }
  }
}

// ---------------- column stats (merged proj+mlp, 16 chunks of 128 rows) ----------------
__global__ void stats1_all(const float* __restrict__ pw, const float* __restrict__ mw,
                           float* __restrict__ ps, float* __restrict__ ps2,
                           float* __restrict__ ms, float* __restrict__ ms2)
{
  const int bx = blockIdx.x, chunk = blockIdx.y;
  const float* W;
  float* os; float* os2; int cols, j;
  if (bx < 8) { W = pw; os = ps; os2 = ps2; cols = 2048; j = bx * 256 + threadIdx.x; }
  else        { W = mw; os = ms; os2 = ms2; cols = 8192; j = (bx - 8) * 256 + threadIdx.x; }
  const float* p = W + (size_t)chunk * 128 * cols + j;
  float s = 0.f, s2 = 0.f;
  for (int i = 0; i < 128; ++i) { float v = p[(size_t)i * cols]; s += v; s2 += v * v; }
  os[chunk * cols + j] = s;
  os2[chunk * cols + j] = s2;
}

// outputs iva = (scale/norm)*alpha, muiva = mu*iva
__global__ void stats2_all(const float* __restrict__ ps, const float* __restrict__ ps2,
                           float* __restrict__ p_iva, float* __restrict__ p_muiva,
                           const float* __restrict__ pscale, const float* __restrict__ outA,
                           const float* __restrict__ ms, const float* __restrict__ ms2,
                           float* __restrict__ m_iva, float* __restrict__ m_muiva,
                           const float* __restrict__ mscale, const float* __restrict__ a2A)
{
  const int bx = blockIdx.x;
  const float* S; const float* S2; float* iva; float* muiva;
  const float* sc; const float* A; int cols, j;
  if (bx < 8) { S = ps; S2 = ps2; iva = p_iva; muiva = p_muiva; sc = pscale; A = outA; cols = 2048; j = bx * 256 + threadIdx.x; }
  else        { S = ms; S2 = ms2; iva = m_iva; muiva = m_muiva; sc = mscale; A = a2A;  cols = 8192; j = (bx - 8) * 256 + threadIdx.x; }
  float s = 0.f, s2 = 0.f;
  for (int c = 0; c < 16; ++c) { s += S[c * cols + j]; s2 += S2[c * cols + j]; }
  float m = s * (1.f / 2048.f);
  float var = s2 - s * m;
  float nn = sqrtf(fmaxf(var, 0.f));
  nn = fmaxf(nn, 1e-12f);
  float iv = (sc[0] / nn) * A[j];
  iva[j] = iv;
  muiva[j] = m * iv;
}

extern "C" void kernel_launch(void* const* d_in, const int* in_sizes, int n_in,
                              void* d_out, int out_size, void* d_ws, size_t ws_size,
                              hipStream_t stream) {
  const float* x          = (const float*)d_in[0];
  const float* cosT       = (const float*)d_in[1];
  const float* sinT       = (const float*)d_in[2];
  const float* attn_w     = (const float*)d_in[3];
  const float* proj_w     = (const float*)d_in[4];
  const float* proj_scale = (const float*)d_in[5];
  const float* fc_w       = (const float*)d_in[6];
  const float* mlp_proj_w = (const float*)d_in[7];
  const float* mlp_scale  = (const float*)d_in[8];
  const float* in_alpha   = (const float*)d_in[9];
  const float* in_beta    = (const float*)d_in[10];
  const float* q_alpha    = (const float*)d_in[11];
  const float* q_beta     = (const float*)d_in[12];
  const float* k_alpha    = (const float*)d_in[13];
  const float* k_beta     = (const float*)d_in[14];
  const float* out_alpha  = (const float*)d_in[15];
  const float* out_beta   = (const float*)d_in[16];
  const float* act1_alpha = (const float*)d_in[17];
  const float* act1_beta  = (const float*)d_in[18];
  const float* act2_alpha = (const float*)d_in[19];
  const float* act2_beta  = (const float*)d_in[20];

  char* cur = (char*)d_ws;
  auto alloc = [&](size_t b) { void* p = cur; cur += (b + 255) & ~(size_t)255; return p; };

  // i8 weights & activations
  char* attn_q = (char*)alloc((size_t)3072 * 2048);
  char* fc_q   = (char*)alloc((size_t)8192 * 2048);
  char* proj_q = (char*)alloc((size_t)2048 * 2048);
  char* mlp_q  = (char*)alloc((size_t)2048 * 8192);
  char* h_in   = (char*)alloc((size_t)2048 * 2048);
  char* h_y    = (char*)alloc((size_t)2048 * 2048);
  char* h2     = (char*)alloc((size_t)2048 * 2048);
  char* h3     = (char*)alloc((size_t)2048 * 8192);
  // bf16 attention operands
  ushort* qbuf  = (ushort*)alloc((size_t)HQ * TT * DD * 2);
  ushort* kbuf  = (ushort*)alloc((size_t)GG * TT * DD * 2);
  ushort* vtbuf = (ushort*)alloc((size_t)GG * DD * TT * 2);
  // f32
  float* x2 = (float*)alloc((size_t)2048 * 2048 * 4);
  // bf16 split-K partial planes
  ushort* qkv_parts  = (ushort*)alloc((size_t)2 * 2048 * 3072 * 2);
  ushort* proj_parts = (ushort*)alloc((size_t)4 * 2048 * 2048 * 2);
  ushort* mlp_parts  = (ushort*)alloc((size_t)4 * 2048 * 2048 * 2);
  // stats + scales
  float* pp_s  = (float*)alloc(16 * 2048 * 4);
  float* pp_s2 = (float*)alloc(16 * 2048 * 4);
  float* mp_s  = (float*)alloc(16 * 8192 * 4);
  float* mp_s2 = (float*)alloc(16 * 8192 * 4);
  float* p_iva   = (float*)alloc(2048 * 4);
  float* p_muiva = (float*)alloc(2048 * 4);
  float* m_iva   = (float*)alloc(8192 * 4);
  float* m_muiva = (float*)alloc(8192 * 4);
  float* s_all = (float*)alloc(15360 * 4);

  const size_t PLANE_QKV = (size_t)2048 * 3072;
  const size_t PLANE     = (size_t)2048 * 2048;

  float* s_attn = s_all;
  float* s_fc   = s_all + 3072;
  float* s_proj = s_all + 11264;
  float* s_mlp  = s_all + 13312;

  // prep: stats -> fused rowmax+quant (+h_in)
  stats1_all<<<dim3(40, 16), 256, 0, stream>>>(proj_w, mlp_proj_w, pp_s, pp_s2, mp_s, mp_s2);
  stats2_all<<<40, 256, 0, stream>>>(pp_s, pp_s2, p_iva, p_muiva, proj_scale, out_alpha,
                                     mp_s, mp_s2, m_iva, m_muiva, mlp_scale, act2_alpha);
  quant_fused<<<5888, 256, 0, stream>>>(attn_w, attn_q, fc_w, fc_q, proj_w, proj_q,
                                        mlp_proj_w, mlp_q,
                                        in_alpha, act1_alpha, p_iva, p_muiva,
                                        m_iva, m_muiva, s_all,
                                        x, in_beta, h_in);

  // qkv = h_in @ attn_q^T * s_attn  (split-K x2, bf16 partials; sum fused into rope)
  gemm_i8<3><<<dim3(3072 / 256, 2048 / 256, 2), 512, 0, stream>>>(
      h_in, attn_q, qkv_parts, s_attn, nullptr, 2048, 3072, 2048, 1024);

  // rope + hv -> q,k bf16 ; transpose v  (job-split grid)
  rope_hv_kernel<<<dim3(TT / 64, GG, 6), 256, 0, stream>>>(
      qkv_parts, qkv_parts + PLANE_QKV, cosT, sinT,
      q_alpha, q_beta, k_alpha, k_beta, qbuf, kbuf, vtbuf);

  // fused causal relu attention v4 -> h_y i8 {0,1}
  attn_kernel<<<dim3(TT / 64, HQ), 256, 0, stream>>>(qbuf, kbuf, vtbuf, h_y, out_beta);

  // x2 = x + h_y @ proj_q^T * s_proj (split-K x4), fused h2 = (x2 - act1_beta > 0)
  gemm_i8<3><<<dim3(2048 / 256, 2048 / 256, 4), 512, 0, stream>>>(
      h_y, proj_q, proj_parts, s_proj, nullptr, 2048, 2048, 2048, 512);
  reduce_kernel<4, 1><<<2048, 256, 0, stream>>>(
      proj_parts, proj_parts + PLANE, proj_parts + 2 * PLANE, proj_parts + 3 * PLANE,
      x, x2, h2, act1_beta, 2048 * 2048 / 4, 2048);

  // h3 = (h2 @ fc_q^T * s_fc - act2_beta > 0)  i8
  gemm_i8<1><<<dim3(8192 / 256, 2048 / 256, 1), 512, 0, stream>>>(
      h2, fc_q, h3, s_fc, act2_beta, 2048, 8192, 2048, 2048);

  // out = x2 + h3 @ mlp_q^T * s_mlp (split-K x4)
  gemm_i8<3><<<dim3(8, 8, 4), 512, 0, stream>>>(
      h3, mlp_q, mlp_parts, s_mlp, nullptr, 2048, 2048, 8192, 2048);
  reduce_kernel<4, 2><<<2048, 256, 0, stream>>>(
      mlp_parts, mlp_parts + PLANE, mlp_parts + 2 * PLANE, mlp_parts + 3 * PLANE,
      x2, (float*)d_out, nullptr, nullptr, 2048 * 2048 / 4, 1);
}

// Round 17
// 265.989 us; speedup vs baseline: 1.0014x; 1.0014x over previous
//
#include <hip/hip_runtime.h>

typedef __attribute__((ext_vector_type(8))) short short8;
typedef __attribute__((ext_vector_type(4))) float f32x4;
typedef __attribute__((ext_vector_type(4))) int i32x4;

constexpr int TT = 2048, CC = 2048, HQ = 16, GG = 4, DD = 128, IC = 8192;

__device__ __forceinline__ ushort f2b(float f) {
  union { float f; unsigned u; } v; v.f = f;
  unsigned r = v.u + 0x7fffu + ((v.u >> 16) & 1u);
  return (ushort)(r >> 16);
}
__device__ __forceinline__ float b2f(ushort u) {
  union { unsigned u; float f; } v; v.u = ((unsigned)u) << 16; return v.f;
}
__device__ __forceinline__ char q8(float eff, float r) {
  float q = rintf(eff * r);
  q = fminf(fmaxf(q, -127.f), 127.f);
  return (char)(int)q;
}
__device__ __forceinline__ unsigned cvt_pk_bf16(float a, float b) {
  unsigned r;
  asm("v_cvt_pk_bf16_f32 %0, %1, %2" : "=v"(r) : "v"(a), "v"(b));
  return r;
}

__device__ __forceinline__ void gload16(const void* g, void* l) {
  __builtin_amdgcn_global_load_lds(
      (const __attribute__((address_space(1))) void*)g,
      (__attribute__((address_space(3))) void*)l, 16, 0, 0);
}

#define BAR()    __builtin_amdgcn_s_barrier()
#define PRIO1()  __builtin_amdgcn_s_setprio(1)
#define PRIO0()  __builtin_amdgcn_s_setprio(0)

// ====== 256x256 i8 GEMM, R7 pipeline clone: C[M,N] = (A{0,1} @ Bq^T) * s[n] ======
template<int EPI>
__global__ __launch_bounds__(512, 2)
void gemm_i8(const char* __restrict__ A, const char* __restrict__ B,
             void* __restrict__ C0, const float* __restrict__ s,
             const float* __restrict__ beta, int M, int N, int K, int kc)
{
  __shared__ alignas(16) char lds[131072];
  const int tid = threadIdx.x;
  const int l = tid & 63, w = tid >> 6;
  const int fl = l & 15, fh = l >> 4;
  const int wrm = w >> 2, wcn = w & 3;
  const int m0 = blockIdx.y * 256, n0 = blockIdx.x * 256;
  const int kBeg = blockIdx.z * kc;
  const int kEnd = (kBeg + kc < K) ? kBeg + kc : K;
  const int nt = (kEnd - kBeg) >> 7;

  i32x4 acc[8][4] = {};

  const int srow = tid >> 3;
  const int scol = ((tid & 7) ^ (srow & 7)) * 16;
  const char* Ag = A + (size_t)(m0 + srow) * K + kBeg + scol;
  const char* Bg = B + (size_t)(n0 + srow) * K + kBeg + scol;

  auto stage_half = [&](int tile, int h) {
    const char* base = (h < 2) ? Ag : Bg;
    const int half = h & 1;
    const char* g = base + (size_t)(half * 128) * K + tile * 128;
    char* d = lds + (tile & 1) * 65536 + ((h < 2) ? 0 : 32768) + half * 16384 + tid * 16;
    gload16(g, d);
    gload16(g + (size_t)64 * K, d + 8192);
  };

  auto readA = [&](i32x4 (&dst)[4][2], int buf, int mofs) {
#pragma unroll
    for (int mf = 0; mf < 4; ++mf)
#pragma unroll
      for (int ks = 0; ks < 2; ++ks) {
        int row = wrm * 128 + (mofs + mf) * 16 + fl;
        dst[mf][ks] = *(const i32x4*)(lds + buf * 65536 + row * 128 +
                                      (((ks * 4 + fh) ^ (row & 7)) * 16));
      }
  };
  auto readB = [&](i32x4 (&dst)[2][2], int buf, int nofs) {
#pragma unroll
    for (int nf = 0; nf < 2; ++nf)
#pragma unroll
      for (int ks = 0; ks < 2; ++ks) {
        int row = wcn * 64 + (nofs + nf) * 16 + fl;
        dst[nf][ks] = *(const i32x4*)(lds + buf * 65536 + 32768 + row * 128 +
                                      (((ks * 4 + fh) ^ (row & 7)) * 16));
      }
  };
  auto mmQ = [&](i32x4 (&a)[4][2], i32x4 (&b)[2][2], int mo, int no) {
    PRIO1();
#pragma unroll
    for (int mf = 0; mf < 4; ++mf)
#pragma unroll
      for (int nf = 0; nf < 2; ++nf)
#pragma unroll
        for (int ks = 0; ks < 2; ++ks)
          acc[mo + mf][no + nf] = __builtin_amdgcn_mfma_i32_16x16x64_i8(
              a[mf][ks], b[nf][ks], acc[mo + mf][no + nf], 0, 0, 0);
    PRIO0();
  };

  stage_half(0, 0); stage_half(0, 1); stage_half(0, 2); stage_half(0, 3);
  if (nt > 1) {
    stage_half(1, 2); stage_half(1, 3);
    asm volatile("s_waitcnt vmcnt(4)" ::: "memory");
  } else {
    asm volatile("s_waitcnt vmcnt(0)" ::: "memory");
  }
  BAR();

  for (int t = 0; t < nt; ++t) {
    const int buf = t & 1;
    i32x4 A0[4][2], A1[4][2], B0[2][2], B1[2][2];

    readA(A0, buf, 0);
    readB(B0, buf, 0);
    if (t + 1 < nt) stage_half(t + 1, 0);
    BAR();
    mmQ(A0, B0, 0, 0);

    readB(B1, buf, 2);
    if (t + 1 < nt) stage_half(t + 1, 1);
    BAR();
    mmQ(A0, B1, 0, 2);

    readA(A1, buf, 4);
    BAR();
    mmQ(A1, B0, 4, 0);

    if (t + 2 < nt) { stage_half(t + 2, 2); stage_half(t + 2, 3); }
    if (t <= nt - 3) asm volatile("s_waitcnt vmcnt(4)" ::: "memory");
    else             asm volatile("s_waitcnt vmcnt(0)" ::: "memory");
    BAR();
    mmQ(A1, B1, 4, 2);
  }

  const int orow0 = m0 + wrm * 128 + fh * 4;
  const int ocol0 = n0 + wcn * 64 + fl;
#pragma unroll
  for (int mf = 0; mf < 8; ++mf) {
#pragma unroll
    for (int nf = 0; nf < 4; ++nf) {
      const int c = ocol0 + nf * 16;
      const float sc = s[c];
#pragma unroll
      for (int j = 0; j < 4; ++j) {
        const int r = orow0 + mf * 16 + j;
        const size_t o = (size_t)r * N + c;
        float v = (float)acc[mf][nf][j] * sc;
        if constexpr (EPI == 1) {
          ((char*)C0)[o] = (v - beta[c] > 0.f) ? (char)1 : (char)0;
        } else {
          ((ushort*)C0 + (size_t)blockIdx.z * M * N)[o] = f2b(v);
        }
      }
    }
  }
}

// ---------------- split-K reduce: bf16 partial planes ----------------
template<int NS, int MODE>
__global__ void reduce_kernel(const ushort* p0, const ushort* p1, const ushort* p2, const ushort* p3,
                              const float* resid, float* outf, char* outb,
                              const float* beta, int n4, int cols)
{
  const ushort* ps[4] = {p0, p1, p2, p3};
  for (int i = blockIdx.x * blockDim.x + threadIdx.x; i < n4; i += gridDim.x * blockDim.x) {
    float4 s = ((const float4*)resid)[i];
#pragma unroll
    for (int z = 0; z < NS; ++z) {
      ushort4 q = ((const ushort4*)ps[z])[i];
      s.x += b2f(q.x); s.y += b2f(q.y); s.z += b2f(q.z); s.w += b2f(q.w);
    }
    ((float4*)outf)[i] = s;
    if constexpr (MODE == 1) {
      int c = (i * 4) & (cols - 1);
      char4 r;
      r.x = (s.x - beta[c] > 0.f) ? 1 : 0;
      r.y = (s.y - beta[c + 1] > 0.f) ? 1 : 0;
      r.z = (s.z - beta[c + 2] > 0.f) ? 1 : 0;
      r.w = (s.w - beta[c + 3] > 0.f) ? 1 : 0;
      ((char4*)outb)[i] = r;
    }
  }
}

// ---- attn v4: Q in regs, single-buffered K/V, swapped-QK^T P phase (cvt_pk + b64 writes) ----
__global__ __launch_bounds__(256, 4)
void attn_kernel(const ushort* __restrict__ qb, const ushort* __restrict__ kb,
                 const ushort* __restrict__ vt, char* __restrict__ hy,
                 const float* __restrict__ obeta)
{
  __shared__ alignas(16) ushort Ks[64 * 128];   // [s][d] swizzled, 16KB
  __shared__ alignas(16) ushort Vs[128 * 64];   // [d][s] swizzled, 16KB
  __shared__ alignas(16) ushort Ps[64 * 64];    // [q][s] swizzled, 8KB
  const int bx = blockIdx.x;
  const int h = blockIdx.y;
  const int qi = (h & 8) ? bx : (31 - bx);
  const int g = h >> 2;
  const int q0 = qi * 64;
  const int tid = threadIdx.x;
  const int w = tid >> 6, l = tid & 63;
  const int fl = l & 15, fh = l >> 4;

  auto stageK = [&](int s0t) {
#pragma unroll
    for (int i = 0; i < 4; ++i) {
      int row = w * 16 + i * 4 + (l >> 4);
      int c16 = (l & 15) ^ (row & 7);
      gload16(kb + (size_t)g * TT * DD + (size_t)(s0t + row) * DD + c16 * 8,
              (char*)Ks + (w << 12) + (i << 10) + (l << 4));
    }
  };
  auto stageV = [&](int s0t) {
#pragma unroll
    for (int i = 0; i < 4; ++i) {
      int d = w * 32 + i * 8 + (l >> 3);
      int c16 = (l & 7) ^ (d & 7);
      gload16(vt + (size_t)g * DD * TT + (size_t)d * TT + s0t + c16 * 8,
              (char*)Vs + (w << 12) + (i << 10) + (l << 4));
    }
  };

  // Q fragments -> registers
  short8 qf[4];
  {
    const ushort* qp = qb + (size_t)h * TT * DD + (size_t)(q0 + w * 16 + fl) * DD + fh * 8;
#pragma unroll
    for (int ks = 0; ks < 4; ++ks) qf[ks] = *(const short8*)(qp + ks * 32);
  }

  const int prow = w * 16 + fl;       // this lane's q-row (within block)
  const int qg = q0 + prow;           // global q index
  f32x4 oacc[8] = {};

  for (int s0 = 0; s0 <= q0; s0 += 64) {
    stageK(s0); stageV(s0);
    asm volatile("s_waitcnt vmcnt(0)" ::: "memory");
    BAR();

    // S^T = K Q^T : lane holds S[s0+n*16+fh*4+j][qg] for j=0..3, n=0..3
    f32x4 sacc[4] = {};
#pragma unroll
    for (int ks = 0; ks < 4; ++ks) {
#pragma unroll
      for (int n = 0; n < 4; ++n) {
        int krow = n * 16 + fl;
        int slotB = (ks * 4 + fh) ^ (krow & 7);
        short8 kf = *(const short8*)((char*)Ks + krow * 256 + slotB * 16);
        sacc[n] = __builtin_amdgcn_mfma_f32_16x16x32_bf16(kf, qf[ks], sacc[n], 0, 0, 0);
      }
    }

    // P row is lane-local: relu(/mask) -> pack pairs -> 4x ds_write_b64
    const bool diag = (s0 == q0);
#pragma unroll
    for (int n = 0; n < 4; ++n) {
      float p[4];
#pragma unroll
      for (int j = 0; j < 4; ++j) {
        float v = sacc[n][j] * 0.0078125f;
        v = fmaxf(v, 0.f);
        if (diag) {
          int sg = s0 + n * 16 + fh * 4 + j;
          if (sg > qg) v = 0.f;
        }
        p[j] = v;
      }
      unsigned lo = cvt_pk_bf16(p[0], p[1]);
      unsigned hi = cvt_pk_bf16(p[2], p[3]);
      int slot = ((n * 2 + (fh >> 1)) ^ (prow & 7));
      char* addr = (char*)Ps + prow * 128 + slot * 16 + ((fh & 1) << 3);
      uint2 val; val.x = lo; val.y = hi;
      *(uint2*)addr = val;
    }

    // O += P V
#pragma unroll
    for (int ks = 0; ks < 2; ++ks) {
      int slotA = (ks * 4 + fh) ^ (prow & 7);
      short8 pa = *(const short8*)((char*)Ps + prow * 128 + slotA * 16);
#pragma unroll
      for (int n = 0; n < 8; ++n) {
        int vrow = n * 16 + fl;
        int slotB = (ks * 4 + fh) ^ (vrow & 7);
        short8 vb = *(const short8*)((char*)Vs + vrow * 128 + slotB * 16);
        oacc[n] = __builtin_amdgcn_mfma_f32_16x16x32_bf16(pa, vb, oacc[n], 0, 0, 0);
      }
    }

    BAR();   // all reads of Ks/Vs done before next iteration's stage
  }

#pragma unroll
  for (int n = 0; n < 8; ++n) {
    const int c = h * DD + n * 16 + fl;
    const float be = obeta[c];
#pragma unroll
    for (int j = 0; j < 4; ++j) {
      const int tq = q0 + w * 16 + fh * 4 + j;
      float v = oacc[n][j];
      hy[(size_t)tq * CC + c] = (v - be > 0.f) ? (char)1 : (char)0;
    }
  }
}

// ---------- rope + hv on q/k, transpose+cast v ; split across blockIdx.z ----------
__global__ __launch_bounds__(256)
void rope_hv_kernel(const ushort* __restrict__ qp0, const ushort* __restrict__ qp1,
                    const float* __restrict__ cs, const float* __restrict__ sn,
                    const float* __restrict__ qalpha, const float* __restrict__ qbeta,
                    const float* __restrict__ kalpha, const float* __restrict__ kbeta,
                    ushort* __restrict__ qb, ushort* __restrict__ kb,
                    ushort* __restrict__ vt)
{
  __shared__ ushort Vsh[64][129];
  const int t0 = blockIdx.x * 64, g = blockIdx.y, job = blockIdx.z;
  const int tid = threadIdx.x;
  if (job < 5) {
    const int hh = job;
    const float* alpha = (hh < 4) ? qalpha : kalpha;
    const float* beta = (hh < 4) ? qbeta : kbeta;
    const int hoff = (hh < 4) ? hh * 128 : 512;
    for (int it = 0; it < 16; ++it) {
      int idx = it * 256 + tid;
      int tr = idx >> 6, dd = idx & 63;
      size_t base = (size_t)(t0 + tr) * 3072 + g * 768 + hoff;
      float x1 = b2f(qp0[base + dd]) + b2f(qp1[base + dd]);
      float x2 = b2f(qp0[base + 64 + dd]) + b2f(qp1[base + 64 + dd]);
      float c = cs[(size_t)(t0 + tr) * 64 + dd];
      float s = sn[(size_t)(t0 + tr) * 64 + dd];
      float o1 = x1 * c - x2 * s, o2 = x1 * s + x2 * c;
      ushort b1 = (o1 - beta[dd] > 0.f) ? f2b(alpha[dd]) : (ushort)0;
      ushort b2 = (o2 - beta[64 + dd] > 0.f) ? f2b(alpha[64 + dd]) : (ushort)0;
      if (hh < 4) {
        size_t o = ((size_t)(g * 4 + hh) * TT + t0 + tr) * DD;
        qb[o + dd] = b1;
        qb[o + 64 + dd] = b2;
      } else {
        size_t o = ((size_t)g * TT + t0 + tr) * DD;
        kb[o + dd] = b1;
        kb[o + 64 + dd] = b2;
      }
    }
  } else {
    for (int it = 0; it < 32; ++it) {
      int idx = it * 256 + tid;
      int tr = idx >> 7, d = idx & 127;
      size_t src = (size_t)(t0 + tr) * 3072 + g * 768 + 640 + d;
      Vsh[tr][d] = f2b(b2f(qp0[src]) + b2f(qp1[src]));
    }
    __syncthreads();
    for (int it = 0; it < 32; ++it) {
      int idx = it * 256 + tid;
      int d = idx >> 6, tl = idx & 63;
      vt[((size_t)g * DD + d) * TT + t0 + tl] = Vsh[tl][d];
    }
  }
}

// ======== quant v3: single GLOBAL pass; effective weights buffered in LDS ========
// Pass 1: read row once, compute eff, ds_write_b128 to per-wave 8KB LDS region, track max.
// Pass 2: ds_read_b128 back, quantize, store i8. Forces one global read regardless of
// register allocation (R15/R16: compiler re-read global at 32-36 VGPR).
__global__ __launch_bounds__(256, 4)
void quant_fused(const float* __restrict__ attn_w, char* __restrict__ attn_q,
                 const float* __restrict__ fc_w, char* __restrict__ fc_q,
                 const float* __restrict__ proj_w, char* __restrict__ proj_q,
                 const float* __restrict__ mlp_w, char* __restrict__ mlp_q,
                 const float* __restrict__ inA, const float* __restrict__ a1A,
                 const float* __restrict__ p_iva, const float* __restrict__ p_muiva,
                 const float* __restrict__ m_iva, const float* __restrict__ m_muiva,
                 float* __restrict__ s_all,
                 const float* __restrict__ x, const float* __restrict__ ib,
                 char* __restrict__ h_in)
{
  __shared__ alignas(16) float efs[8192];   // 32KB: 4 waves x 2048 floats
  __shared__ float wmax[4];
  const int bx = blockIdx.x;
  const int tid = threadIdx.x;
  const int wv = tid >> 6, lane = tid & 63;
  float4* eflds = (float4*)(efs + wv * 2048);   // per-wave region, 512 float4

  if (bx < 3328) {
    const float* W; char* Q; const float4* A4;
    const float4* MUIVA4 = nullptr;
    int row, sofs;
    if (bx < 768)       { W = attn_w; Q = attn_q; A4 = (const float4*)inA;   row = bx * 4 + wv;          sofs = 0; }
    else if (bx < 2816) { W = fc_w;   Q = fc_q;   A4 = (const float4*)a1A;   row = (bx - 768) * 4 + wv;  sofs = 3072; }
    else                { W = proj_w; Q = proj_q; A4 = (const float4*)p_iva; row = (bx - 2816) * 4 + wv; sofs = 11264;
                          MUIVA4 = (const float4*)p_muiva; }
    const float4* src = (const float4*)(W + (size_t)row * 2048);
    char4* dst = (char4*)(Q + (size_t)row * 2048);
    float m = 0.f;
#pragma unroll
    for (int it = 0; it < 8; ++it) {
      int i = it * 64 + lane;
      float4 v = src[i];
      float4 a = A4[i];
      float4 e;
      if (MUIVA4) {
        float4 mv = MUIVA4[i];
        e.x = fmaf(v.x, a.x, -mv.x);
        e.y = fmaf(v.y, a.y, -mv.y);
        e.z = fmaf(v.z, a.z, -mv.z);
        e.w = fmaf(v.w, a.w, -mv.w);
      } else {
        e.x = v.x * a.x; e.y = v.y * a.y; e.z = v.z * a.z; e.w = v.w * a.w;
      }
      eflds[i] = e;
      m = fmaxf(m, fmaxf(fmaxf(fabsf(e.x), fabsf(e.y)), fmaxf(fabsf(e.z), fabsf(e.w))));
    }
    for (int mask = 32; mask; mask >>= 1) m = fmaxf(m, __shfl_xor(m, mask));
    if (lane == 0) s_all[sofs + row] = m * (1.f / 127.f);
    const float r = (m > 0.f) ? 127.f / m : 0.f;
#pragma unroll
    for (int it = 0; it < 8; ++it) {
      int i = it * 64 + lane;
      float4 e = eflds[i];
      char4 q;
      q.x = q8(e.x, r); q.y = q8(e.y, r);
      q.z = q8(e.z, r); q.w = q8(e.w, r);
      dst[i] = q;
    }
  } else if (bx < 5376) {
    const int row = bx - 3328;
    const float4* src = (const float4*)(mlp_w + (size_t)row * 8192);
    const float4* A4 = (const float4*)m_iva;
    const float4* MUIVA4 = (const float4*)m_muiva;
    char4* dst = (char4*)(mlp_q + (size_t)row * 8192);
    float m = 0.f;
#pragma unroll
    for (int it = 0; it < 8; ++it) {
      int li = it * 64 + lane;              // index within wave's 512-float4 slice
      int i = wv * 512 + li;                // global float4 index in the row
      float4 v = src[i];
      float4 a = A4[i], mv = MUIVA4[i];
      float4 e;
      e.x = fmaf(v.x, a.x, -mv.x);
      e.y = fmaf(v.y, a.y, -mv.y);
      e.z = fmaf(v.z, a.z, -mv.z);
      e.w = fmaf(v.w, a.w, -mv.w);
      eflds[li] = e;
      m = fmaxf(m, fmaxf(fmaxf(fabsf(e.x), fabsf(e.y)), fmaxf(fabsf(e.z), fabsf(e.w))));
    }
    for (int mask = 32; mask; mask >>= 1) m = fmaxf(m, __shfl_xor(m, mask));
    if (lane == 0) wmax[wv] = m;
    __syncthreads();
    m = fmaxf(fmaxf(wmax[0], wmax[1]), fmaxf(wmax[2], wmax[3]));
    if (tid == 0) s_all[13312 + row] = m * (1.f / 127.f);
    const float r = (m > 0.f) ? 127.f / m : 0.f;
#pragma unroll
    for (int it = 0; it < 8; ++it) {
      int li = it * 64 + lane;
      int i = wv * 512 + li;
      float4 e = eflds[li];
      char4 q;
      q.x = q8(e.x, r); q.y = q8(e.y, r);
      q.z = q8(e.z, r); q.w = q8(e.w, r);
      dst[i] = q;
    }
  } else {
    const int blk = bx - 5376;
    const int stride = 512 * 256;
    const float4* ib4 = (const float4*)ib;
    for (int i = blk * 256 + tid; i < 2048 * 2048 / 4; i += stride) {
      float4 v = ((const float4*)x)[i];
      float4 b = ib4[i & 511];
      char4 q;
      q.x = (v.x - b.x > 0.f) ? 1 : 0;
      q.y = (v.y - b.y > 0.f) ? 1 : 0;
      q.z = (v.z - b.z > 0.f) ? 1 : 0;
      q.w = (v.w - b.w > 0.f) ? 1 : 0;
      ((char4*)h_in)[i] = q;
    }
  }
}

// ---------------- column stats (merged proj+mlp, 16 chunks of 128 rows) ----------------
__global__ void stats1_all(const float* __restrict__ pw, const float* __restrict__ mw,
                           float* __restrict__ ps, float* __restrict__ ps2,
                           float* __restrict__ ms, float* __restrict__ ms2)
{
  const int bx = blockIdx.x, chunk = blockIdx.y;
  const float* W;
  float* os; float* os2; int cols, j;
  if (bx < 8) { W = pw; os = ps; os2 = ps2; cols = 2048; j = bx * 256 + threadIdx.x; }
  else        { W = mw; os = ms; os2 = ms2; cols = 8192; j = (bx - 8) * 256 + threadIdx.x; }
  const float* p = W + (size_t)chunk * 128 * cols + j;
  float s = 0.f, s2 = 0.f;
  for (int i = 0; i < 128; ++i) { float v = p[(size_t)i * cols]; s += v; s2 += v * v; }
  os[chunk * cols + j] = s;
  os2[chunk * cols + j] = s2;
}

// outputs iva = (scale/norm)*alpha, muiva = mu*iva
__global__ void stats2_all(const float* __restrict__ ps, const float* __restrict__ ps2,
                           float* __restrict__ p_iva, float* __restrict__ p_muiva,
                           const float* __restrict__ pscale, const float* __restrict__ outA,
                           const float* __restrict__ ms, const float* __restrict__ ms2,
                           float* __restrict__ m_iva, float* __restrict__ m_muiva,
                           const float* __restrict__ mscale, const float* __restrict__ a2A)
{
  const int bx = blockIdx.x;
  const float* S; const float* S2; float* iva; float* muiva;
  const float* sc; const float* A; int cols, j;
  if (bx < 8) { S = ps; S2 = ps2; iva = p_iva; muiva = p_muiva; sc = pscale; A = outA; cols = 2048; j = bx * 256 + threadIdx.x; }
  else        { S = ms; S2 = ms2; iva = m_iva; muiva = m_muiva; sc = mscale; A = a2A;  cols = 8192; j = (bx - 8) * 256 + threadIdx.x; }
  float s = 0.f, s2 = 0.f;
  for (int c = 0; c < 16; ++c) { s += S[c * cols + j]; s2 += S2[c * cols + j]; }
  float m = s * (1.f / 2048.f);
  float var = s2 - s * m;
  float nn = sqrtf(fmaxf(var, 0.f));
  nn = fmaxf(nn, 1e-12f);
  float iv = (sc[0] / nn) * A[j];
  iva[j] = iv;
  muiva[j] = m * iv;
}

extern "C" void kernel_launch(void* const* d_in, const int* in_sizes, int n_in,
                              void* d_out, int out_size, void* d_ws, size_t ws_size,
                              hipStream_t stream) {
  const float* x          = (const float*)d_in[0];
  const float* cosT       = (const float*)d_in[1];
  const float* sinT       = (const float*)d_in[2];
  const float* attn_w     = (const float*)d_in[3];
  const float* proj_w     = (const float*)d_in[4];
  const float* proj_scale = (const float*)d_in[5];
  const float* fc_w       = (const float*)d_in[6];
  const float* mlp_proj_w = (const float*)d_in[7];
  const float* mlp_scale  = (const float*)d_in[8];
  const float* in_alpha   = (const float*)d_in[9];
  const float* in_beta    = (const float*)d_in[10];
  const float* q_alpha    = (const float*)d_in[11];
  const float* q_beta     = (const float*)d_in[12];
  const float* k_alpha    = (const float*)d_in[13];
  const float* k_beta     = (const float*)d_in[14];
  const float* out_alpha  = (const float*)d_in[15];
  const float* out_beta   = (const float*)d_in[16];
  const float* act1_alpha = (const float*)d_in[17];
  const float* act1_beta  = (const float*)d_in[18];
  const float* act2_alpha = (const float*)d_in[19];
  const float* act2_beta  = (const float*)d_in[20];

  char* cur = (char*)d_ws;
  auto alloc = [&](size_t b) { void* p = cur; cur += (b + 255) & ~(size_t)255; return p; };

  // i8 weights & activations
  char* attn_q = (char*)alloc((size_t)3072 * 2048);
  char* fc_q   = (char*)alloc((size_t)8192 * 2048);
  char* proj_q = (char*)alloc((size_t)2048 * 2048);
  char* mlp_q  = (char*)alloc((size_t)2048 * 8192);
  char* h_in   = (char*)alloc((size_t)2048 * 2048);
  char* h_y    = (char*)alloc((size_t)2048 * 2048);
  char* h2     = (char*)alloc((size_t)2048 * 2048);
  char* h3     = (char*)alloc((size_t)2048 * 8192);
  // bf16 attention operands
  ushort* qbuf  = (ushort*)alloc((size_t)HQ * TT * DD * 2);
  ushort* kbuf  = (ushort*)alloc((size_t)GG * TT * DD * 2);
  ushort* vtbuf = (ushort*)alloc((size_t)GG * DD * TT * 2);
  // f32
  float* x2 = (float*)alloc((size_t)2048 * 2048 * 4);
  // bf16 split-K partial planes
  ushort* qkv_parts  = (ushort*)alloc((size_t)2 * 2048 * 3072 * 2);
  ushort* proj_parts = (ushort*)alloc((size_t)4 * 2048 * 2048 * 2);
  ushort* mlp_parts  = (ushort*)alloc((size_t)4 * 2048 * 2048 * 2);
  // stats + scales
  float* pp_s  = (float*)alloc(16 * 2048 * 4);
  float* pp_s2 = (float*)alloc(16 * 2048 * 4);
  float* mp_s  = (float*)alloc(16 * 8192 * 4);
  float* mp_s2 = (float*)alloc(16 * 8192 * 4);
  float* p_iva   = (float*)alloc(2048 * 4);
  float* p_muiva = (float*)alloc(2048 * 4);
  float* m_iva   = (float*)alloc(8192 * 4);
  float* m_muiva = (float*)alloc(8192 * 4);
  float* s_all = (float*)alloc(15360 * 4);

  const size_t PLANE_QKV = (size_t)2048 * 3072;
  const size_t PLANE     = (size_t)2048 * 2048;

  float* s_attn = s_all;
  float* s_fc   = s_all + 3072;
  float* s_proj = s_all + 11264;
  float* s_mlp  = s_all + 13312;

  // prep: stats -> fused rowmax+quant (+h_in)
  stats1_all<<<dim3(40, 16), 256, 0, stream>>>(proj_w, mlp_proj_w, pp_s, pp_s2, mp_s, mp_s2);
  stats2_all<<<40, 256, 0, stream>>>(pp_s, pp_s2, p_iva, p_muiva, proj_scale, out_alpha,
                                     mp_s, mp_s2, m_iva, m_muiva, mlp_scale, act2_alpha);
  quant_fused<<<5888, 256, 0, stream>>>(attn_w, attn_q, fc_w, fc_q, proj_w, proj_q,
                                        mlp_proj_w, mlp_q,
                                        in_alpha, act1_alpha, p_iva, p_muiva,
                                        m_iva, m_muiva, s_all,
                                        x, in_beta, h_in);

  // qkv = h_in @ attn_q^T * s_attn  (split-K x2, bf16 partials; sum fused into rope)
  gemm_i8<3><<<dim3(3072 / 256, 2048 / 256, 2), 512, 0, stream>>>(
      h_in, attn_q, qkv_parts, s_attn, nullptr, 2048, 3072, 2048, 1024);

  // rope + hv -> q,k bf16 ; transpose v  (job-split grid)
  rope_hv_kernel<<<dim3(TT / 64, GG, 6), 256, 0, stream>>>(
      qkv_parts, qkv_parts + PLANE_QKV, cosT, sinT,
      q_alpha, q_beta, k_alpha, k_beta, qbuf, kbuf, vtbuf);

  // fused causal relu attention v4 -> h_y i8 {0,1}
  attn_kernel<<<dim3(TT / 64, HQ), 256, 0, stream>>>(qbuf, kbuf, vtbuf, h_y, out_beta);

  // x2 = x + h_y @ proj_q^T * s_proj (split-K x4), fused h2 = (x2 - act1_beta > 0)
  gemm_i8<3><<<dim3(2048 / 256, 2048 / 256, 4), 512, 0, stream>>>(
      h_y, proj_q, proj_parts, s_proj, nullptr, 2048, 2048, 2048, 512);
  reduce_kernel<4, 1><<<2048, 256, 0, stream>>>(
      proj_parts, proj_parts + PLANE, proj_parts + 2 * PLANE, proj_parts + 3 * PLANE,
      x, x2, h2, act1_beta, 2048 * 2048 / 4, 2048);

  // h3 = (h2 @ fc_q^T * s_fc - act2_beta > 0)  i8
  gemm_i8<1><<<dim3(8192 / 256, 2048 / 256, 1), 512, 0, stream>>>(
      h2, fc_q, h3, s_fc, act2_beta, 2048, 8192, 2048, 2048);

  // out = x2 + h3 @ mlp_q^T * s_mlp (split-K x4)
  gemm_i8<3><<<dim3(8, 8, 4), 512, 0, stream>>>(
      h3, mlp_q, mlp_parts, s_mlp, nullptr, 2048, 2048, 8192, 2048);
  reduce_kernel<4, 2><<<2048, 256, 0, stream>>>(
      mlp_parts, mlp_parts + PLANE, mlp_parts + 2 * PLANE, mlp_parts + 3 * PLANE,
      x2, (float*)d_out, nullptr, nullptr, 2048 * 2048 / 4, 1);
}

// Round 18
// 263.654 us; speedup vs baseline: 1.0103x; 1.0089x over previous
//
#include <hip/hip_runtime.h>

typedef __attribute__((ext_vector_type(8))) short short8;
typedef __attribute__((ext_vector_type(4))) float f32x4;
typedef __attribute__((ext_vector_type(4))) int i32x4;

constexpr int TT = 2048, CC = 2048, HQ = 16, GG = 4, DD = 128, IC = 8192;

__device__ __forceinline__ ushort f2b(float f) {
  union { float f; unsigned u; } v; v.f = f;
  unsigned r = v.u + 0x7fffu + ((v.u >> 16) & 1u);
  return (ushort)(r >> 16);
}
__device__ __forceinline__ float b2f(ushort u) {
  union { unsigned u; float f; } v; v.u = ((unsigned)u) << 16; return v.f;
}
__device__ __forceinline__ char q8(float eff, float r) {
  float q = rintf(eff * r);
  q = fminf(fmaxf(q, -127.f), 127.f);
  return (char)(int)q;
}
__device__ __forceinline__ unsigned cvt_pk_bf16(float a, float b) {
  unsigned r;
  asm("v_cvt_pk_bf16_f32 %0, %1, %2" : "=v"(r) : "v"(a), "v"(b));
  return r;
}

__device__ __forceinline__ void gload16(const void* g, void* l) {
  __builtin_amdgcn_global_load_lds(
      (const __attribute__((address_space(1))) void*)g,
      (__attribute__((address_space(3))) void*)l, 16, 0, 0);
}

#define BAR()    __builtin_amdgcn_s_barrier()
#define PRIO1()  __builtin_amdgcn_s_setprio(1)
#define PRIO0()  __builtin_amdgcn_s_setprio(0)

// ====== 256x256 i8 GEMM, R7 pipeline clone: C[M,N] = (A{0,1} @ Bq^T) * s[n] ======
template<int EPI>
__global__ __launch_bounds__(512, 2)
void gemm_i8(const char* __restrict__ A, const char* __restrict__ B,
             void* __restrict__ C0, const float* __restrict__ s,
             const float* __restrict__ beta, int M, int N, int K, int kc)
{
  __shared__ alignas(16) char lds[131072];
  const int tid = threadIdx.x;
  const int l = tid & 63, w = tid >> 6;
  const int fl = l & 15, fh = l >> 4;
  const int wrm = w >> 2, wcn = w & 3;
  const int m0 = blockIdx.y * 256, n0 = blockIdx.x * 256;
  const int kBeg = blockIdx.z * kc;
  const int kEnd = (kBeg + kc < K) ? kBeg + kc : K;
  const int nt = (kEnd - kBeg) >> 7;

  i32x4 acc[8][4] = {};

  const int srow = tid >> 3;
  const int scol = ((tid & 7) ^ (srow & 7)) * 16;
  const char* Ag = A + (size_t)(m0 + srow) * K + kBeg + scol;
  const char* Bg = B + (size_t)(n0 + srow) * K + kBeg + scol;

  auto stage_half = [&](int tile, int h) {
    const char* base = (h < 2) ? Ag : Bg;
    const int half = h & 1;
    const char* g = base + (size_t)(half * 128) * K + tile * 128;
    char* d = lds + (tile & 1) * 65536 + ((h < 2) ? 0 : 32768) + half * 16384 + tid * 16;
    gload16(g, d);
    gload16(g + (size_t)64 * K, d + 8192);
  };

  auto readA = [&](i32x4 (&dst)[4][2], int buf, int mofs) {
#pragma unroll
    for (int mf = 0; mf < 4; ++mf)
#pragma unroll
      for (int ks = 0; ks < 2; ++ks) {
        int row = wrm * 128 + (mofs + mf) * 16 + fl;
        dst[mf][ks] = *(const i32x4*)(lds + buf * 65536 + row * 128 +
                                      (((ks * 4 + fh) ^ (row & 7)) * 16));
      }
  };
  auto readB = [&](i32x4 (&dst)[2][2], int buf, int nofs) {
#pragma unroll
    for (int nf = 0; nf < 2; ++nf)
#pragma unroll
      for (int ks = 0; ks < 2; ++ks) {
        int row = wcn * 64 + (nofs + nf) * 16 + fl;
        dst[nf][ks] = *(const i32x4*)(lds + buf * 65536 + 32768 + row * 128 +
                                      (((ks * 4 + fh) ^ (row & 7)) * 16));
      }
  };
  auto mmQ = [&](i32x4 (&a)[4][2], i32x4 (&b)[2][2], int mo, int no) {
    PRIO1();
#pragma unroll
    for (int mf = 0; mf < 4; ++mf)
#pragma unroll
      for (int nf = 0; nf < 2; ++nf)
#pragma unroll
        for (int ks = 0; ks < 2; ++ks)
          acc[mo + mf][no + nf] = __builtin_amdgcn_mfma_i32_16x16x64_i8(
              a[mf][ks], b[nf][ks], acc[mo + mf][no + nf], 0, 0, 0);
    PRIO0();
  };

  stage_half(0, 0); stage_half(0, 1); stage_half(0, 2); stage_half(0, 3);
  if (nt > 1) {
    stage_half(1, 2); stage_half(1, 3);
    asm volatile("s_waitcnt vmcnt(4)" ::: "memory");
  } else {
    asm volatile("s_waitcnt vmcnt(0)" ::: "memory");
  }
  BAR();

  for (int t = 0; t < nt; ++t) {
    const int buf = t & 1;
    i32x4 A0[4][2], A1[4][2], B0[2][2], B1[2][2];

    readA(A0, buf, 0);
    readB(B0, buf, 0);
    if (t + 1 < nt) stage_half(t + 1, 0);
    BAR();
    mmQ(A0, B0, 0, 0);

    readB(B1, buf, 2);
    if (t + 1 < nt) stage_half(t + 1, 1);
    BAR();
    mmQ(A0, B1, 0, 2);

    readA(A1, buf, 4);
    BAR();
    mmQ(A1, B0, 4, 0);

    if (t + 2 < nt) { stage_half(t + 2, 2); stage_half(t + 2, 3); }
    if (t <= nt - 3) asm volatile("s_waitcnt vmcnt(4)" ::: "memory");
    else             asm volatile("s_waitcnt vmcnt(0)" ::: "memory");
    BAR();
    mmQ(A1, B1, 4, 2);
  }

  const int orow0 = m0 + wrm * 128 + fh * 4;
  const int ocol0 = n0 + wcn * 64 + fl;
#pragma unroll
  for (int mf = 0; mf < 8; ++mf) {
#pragma unroll
    for (int nf = 0; nf < 4; ++nf) {
      const int c = ocol0 + nf * 16;
      const float sc = s[c];
#pragma unroll
      for (int j = 0; j < 4; ++j) {
        const int r = orow0 + mf * 16 + j;
        const size_t o = (size_t)r * N + c;
        float v = (float)acc[mf][nf][j] * sc;
        if constexpr (EPI == 1) {
          ((char*)C0)[o] = (v - beta[c] > 0.f) ? (char)1 : (char)0;
        } else {
          ((ushort*)C0 + (size_t)blockIdx.z * M * N)[o] = f2b(v);
        }
      }
    }
  }
}

// ---------------- split-K reduce: bf16 partial planes ----------------
template<int NS, int MODE>
__global__ void reduce_kernel(const ushort* p0, const ushort* p1, const ushort* p2, const ushort* p3,
                              const float* resid, float* outf, char* outb,
                              const float* beta, int n4, int cols)
{
  const ushort* ps[4] = {p0, p1, p2, p3};
  for (int i = blockIdx.x * blockDim.x + threadIdx.x; i < n4; i += gridDim.x * blockDim.x) {
    float4 s = ((const float4*)resid)[i];
#pragma unroll
    for (int z = 0; z < NS; ++z) {
      ushort4 q = ((const ushort4*)ps[z])[i];
      s.x += b2f(q.x); s.y += b2f(q.y); s.z += b2f(q.z); s.w += b2f(q.w);
    }
    ((float4*)outf)[i] = s;
    if constexpr (MODE == 1) {
      int c = (i * 4) & (cols - 1);
      char4 r;
      r.x = (s.x - beta[c] > 0.f) ? 1 : 0;
      r.y = (s.y - beta[c + 1] > 0.f) ? 1 : 0;
      r.z = (s.z - beta[c + 2] > 0.f) ? 1 : 0;
      r.w = (s.w - beta[c + 3] > 0.f) ? 1 : 0;
      ((char4*)outb)[i] = r;
    }
  }
}

// ---- attn v4: Q in regs, single-buffered K/V, swapped-QK^T P phase (cvt_pk + b64 writes) ----
__global__ __launch_bounds__(256, 4)
void attn_kernel(const ushort* __restrict__ qb, const ushort* __restrict__ kb,
                 const ushort* __restrict__ vt, char* __restrict__ hy,
                 const float* __restrict__ obeta)
{
  __shared__ alignas(16) ushort Ks[64 * 128];
  __shared__ alignas(16) ushort Vs[128 * 64];
  __shared__ alignas(16) ushort Ps[64 * 64];
  const int bx = blockIdx.x;
  const int h = blockIdx.y;
  const int qi = (h & 8) ? bx : (31 - bx);
  const int g = h >> 2;
  const int q0 = qi * 64;
  const int tid = threadIdx.x;
  const int w = tid >> 6, l = tid & 63;
  const int fl = l & 15, fh = l >> 4;

  auto stageK = [&](int s0t) {
#pragma unroll
    for (int i = 0; i < 4; ++i) {
      int row = w * 16 + i * 4 + (l >> 4);
      int c16 = (l & 15) ^ (row & 7);
      gload16(kb + (size_t)g * TT * DD + (size_t)(s0t + row) * DD + c16 * 8,
              (char*)Ks + (w << 12) + (i << 10) + (l << 4));
    }
  };
  auto stageV = [&](int s0t) {
#pragma unroll
    for (int i = 0; i < 4; ++i) {
      int d = w * 32 + i * 8 + (l >> 3);
      int c16 = (l & 7) ^ (d & 7);
      gload16(vt + (size_t)g * DD * TT + (size_t)d * TT + s0t + c16 * 8,
              (char*)Vs + (w << 12) + (i << 10) + (l << 4));
    }
  };

  short8 qf[4];
  {
    const ushort* qp = qb + (size_t)h * TT * DD + (size_t)(q0 + w * 16 + fl) * DD + fh * 8;
#pragma unroll
    for (int ks = 0; ks < 4; ++ks) qf[ks] = *(const short8*)(qp + ks * 32);
  }

  const int prow = w * 16 + fl;
  const int qg = q0 + prow;
  f32x4 oacc[8] = {};

  for (int s0 = 0; s0 <= q0; s0 += 64) {
    stageK(s0); stageV(s0);
    asm volatile("s_waitcnt vmcnt(0)" ::: "memory");
    BAR();

    f32x4 sacc[4] = {};
#pragma unroll
    for (int ks = 0; ks < 4; ++ks) {
#pragma unroll
      for (int n = 0; n < 4; ++n) {
        int krow = n * 16 + fl;
        int slotB = (ks * 4 + fh) ^ (krow & 7);
        short8 kf = *(const short8*)((char*)Ks + krow * 256 + slotB * 16);
        sacc[n] = __builtin_amdgcn_mfma_f32_16x16x32_bf16(kf, qf[ks], sacc[n], 0, 0, 0);
      }
    }

    const bool diag = (s0 == q0);
#pragma unroll
    for (int n = 0; n < 4; ++n) {
      float p[4];
#pragma unroll
      for (int j = 0; j < 4; ++j) {
        float v = sacc[n][j] * 0.0078125f;
        v = fmaxf(v, 0.f);
        if (diag) {
          int sg = s0 + n * 16 + fh * 4 + j;
          if (sg > qg) v = 0.f;
        }
        p[j] = v;
      }
      unsigned lo = cvt_pk_bf16(p[0], p[1]);
      unsigned hi = cvt_pk_bf16(p[2], p[3]);
      int slot = ((n * 2 + (fh >> 1)) ^ (prow & 7));
      char* addr = (char*)Ps + prow * 128 + slot * 16 + ((fh & 1) << 3);
      uint2 val; val.x = lo; val.y = hi;
      *(uint2*)addr = val;
    }

#pragma unroll
    for (int ks = 0; ks < 2; ++ks) {
      int slotA = (ks * 4 + fh) ^ (prow & 7);
      short8 pa = *(const short8*)((char*)Ps + prow * 128 + slotA * 16);
#pragma unroll
      for (int n = 0; n < 8; ++n) {
        int vrow = n * 16 + fl;
        int slotB = (ks * 4 + fh) ^ (vrow & 7);
        short8 vb = *(const short8*)((char*)Vs + vrow * 128 + slotB * 16);
        oacc[n] = __builtin_amdgcn_mfma_f32_16x16x32_bf16(pa, vb, oacc[n], 0, 0, 0);
      }
    }

    BAR();
  }

#pragma unroll
  for (int n = 0; n < 8; ++n) {
    const int c = h * DD + n * 16 + fl;
    const float be = obeta[c];
#pragma unroll
    for (int j = 0; j < 4; ++j) {
      const int tq = q0 + w * 16 + fh * 4 + j;
      float v = oacc[n][j];
      hy[(size_t)tq * CC + c] = (v - be > 0.f) ? (char)1 : (char)0;
    }
  }
}

// ---------- rope + hv on q/k, transpose+cast v ; split across blockIdx.z ----------
__global__ __launch_bounds__(256)
void rope_hv_kernel(const ushort* __restrict__ qp0, const ushort* __restrict__ qp1,
                    const float* __restrict__ cs, const float* __restrict__ sn,
                    const float* __restrict__ qalpha, const float* __restrict__ qbeta,
                    const float* __restrict__ kalpha, const float* __restrict__ kbeta,
                    ushort* __restrict__ qb, ushort* __restrict__ kb,
                    ushort* __restrict__ vt)
{
  __shared__ ushort Vsh[64][129];
  const int t0 = blockIdx.x * 64, g = blockIdx.y, job = blockIdx.z;
  const int tid = threadIdx.x;
  if (job < 5) {
    const int hh = job;
    const float* alpha = (hh < 4) ? qalpha : kalpha;
    const float* beta = (hh < 4) ? qbeta : kbeta;
    const int hoff = (hh < 4) ? hh * 128 : 512;
    for (int it = 0; it < 16; ++it) {
      int idx = it * 256 + tid;
      int tr = idx >> 6, dd = idx & 63;
      size_t base = (size_t)(t0 + tr) * 3072 + g * 768 + hoff;
      float x1 = b2f(qp0[base + dd]) + b2f(qp1[base + dd]);
      float x2 = b2f(qp0[base + 64 + dd]) + b2f(qp1[base + 64 + dd]);
      float c = cs[(size_t)(t0 + tr) * 64 + dd];
      float s = sn[(size_t)(t0 + tr) * 64 + dd];
      float o1 = x1 * c - x2 * s, o2 = x1 * s + x2 * c;
      ushort b1 = (o1 - beta[dd] > 0.f) ? f2b(alpha[dd]) : (ushort)0;
      ushort b2 = (o2 - beta[64 + dd] > 0.f) ? f2b(alpha[64 + dd]) : (ushort)0;
      if (hh < 4) {
        size_t o = ((size_t)(g * 4 + hh) * TT + t0 + tr) * DD;
        qb[o + dd] = b1;
        qb[o + 64 + dd] = b2;
      } else {
        size_t o = ((size_t)g * TT + t0 + tr) * DD;
        kb[o + dd] = b1;
        kb[o + 64 + dd] = b2;
      }
    }
  } else {
    for (int it = 0; it < 32; ++it) {
      int idx = it * 256 + tid;
      int tr = idx >> 7, d = idx & 127;
      size_t src = (size_t)(t0 + tr) * 3072 + g * 768 + 640 + d;
      Vsh[tr][d] = f2b(b2f(qp0[src]) + b2f(qp1[src]));
    }
    __syncthreads();
    for (int it = 0; it < 32; ++it) {
      int idx = it * 256 + tid;
      int d = idx >> 6, tl = idx & 63;
      vt[((size_t)g * DD + d) * TT + t0 + tl] = Vsh[tl][d];
    }
  }
}

// ======== prep1: attn-quant + fc-quant + h_in + stats1 column sums, ONE dispatch ========
// blocks: [0,768) attn rows x4 | [768,2816) fc rows x4 | [2816,3328) h_in | [3328,3968) stats1
__global__ __launch_bounds__(256, 4)
void prep1_kernel(const float* __restrict__ attn_w, char* __restrict__ attn_q,
                  const float* __restrict__ fc_w, char* __restrict__ fc_q,
                  const float* __restrict__ inA, const float* __restrict__ a1A,
                  float* __restrict__ s_all,
                  const float* __restrict__ x, const float* __restrict__ ib,
                  char* __restrict__ h_in,
                  const float* __restrict__ pw, const float* __restrict__ mw,
                  float* __restrict__ ps, float* __restrict__ ps2,
                  float* __restrict__ ms, float* __restrict__ ms2)
{
  __shared__ alignas(16) float efs[8192];   // 32KB: 4 waves x 2048 floats
  const int bx = blockIdx.x;
  const int tid = threadIdx.x;
  const int wv = tid >> 6, lane = tid & 63;
  float4* eflds = (float4*)(efs + wv * 2048);

  if (bx < 2816) {
    const float* W; char* Q; const float4* A4;
    int row, sofs;
    if (bx < 768) { W = attn_w; Q = attn_q; A4 = (const float4*)inA; row = bx * 4 + wv;         sofs = 0; }
    else          { W = fc_w;   Q = fc_q;   A4 = (const float4*)a1A; row = (bx - 768) * 4 + wv; sofs = 3072; }
    const float4* src = (const float4*)(W + (size_t)row * 2048);
    char4* dst = (char4*)(Q + (size_t)row * 2048);
    float m = 0.f;
#pragma unroll
    for (int it = 0; it < 8; ++it) {
      int i = it * 64 + lane;
      float4 v = src[i];
      float4 a = A4[i];
      float4 e;
      e.x = v.x * a.x; e.y = v.y * a.y; e.z = v.z * a.z; e.w = v.w * a.w;
      eflds[i] = e;
      m = fmaxf(m, fmaxf(fmaxf(fabsf(e.x), fabsf(e.y)), fmaxf(fabsf(e.z), fabsf(e.w))));
    }
    for (int mask = 32; mask; mask >>= 1) m = fmaxf(m, __shfl_xor(m, mask));
    if (lane == 0) s_all[sofs + row] = m * (1.f / 127.f);
    const float r = (m > 0.f) ? 127.f / m : 0.f;
#pragma unroll
    for (int it = 0; it < 8; ++it) {
      int i = it * 64 + lane;
      float4 e = eflds[i];
      char4 q;
      q.x = q8(e.x, r); q.y = q8(e.y, r);
      q.z = q8(e.z, r); q.w = q8(e.w, r);
      dst[i] = q;
    }
  } else if (bx < 3328) {
    const int blk = bx - 2816;
    const int stride = 512 * 256;
    const float4* ib4 = (const float4*)ib;
    for (int i = blk * 256 + tid; i < 2048 * 2048 / 4; i += stride) {
      float4 v = ((const float4*)x)[i];
      float4 b = ib4[i & 511];
      char4 q;
      q.x = (v.x - b.x > 0.f) ? 1 : 0;
      q.y = (v.y - b.y > 0.f) ? 1 : 0;
      q.z = (v.z - b.z > 0.f) ? 1 : 0;
      q.w = (v.w - b.w > 0.f) ? 1 : 0;
      ((char4*)h_in)[i] = q;
    }
  } else {
    // stats1: 640 jobs = 40 column-groups x 16 row-chunks of 128
    const int jb = bx - 3328;
    const int sb = jb % 40;
    const int chunk = jb / 40;
    const float* W;
    float* os; float* os2; int cols, j;
    if (sb < 8) { W = pw; os = ps; os2 = ps2; cols = 2048; j = sb * 256 + tid; }
    else        { W = mw; os = ms; os2 = ms2; cols = 8192; j = (sb - 8) * 256 + tid; }
    const float* p = W + (size_t)chunk * 128 * cols + j;
    float s = 0.f, s2 = 0.f;
    for (int i = 0; i < 128; ++i) { float v = p[(size_t)i * cols]; s += v; s2 += v * v; }
    os[chunk * cols + j] = s;
    os2[chunk * cols + j] = s2;
  }
}

// ======== prep2: proj + mlp quant (stats-dependent; reads are L3-hot) ========
// blocks: [0,512) proj rows x4 | [512,2560) mlp 1 row (4-wave split)
__global__ __launch_bounds__(256, 4)
void prep2_kernel(const float* __restrict__ proj_w, char* __restrict__ proj_q,
                  const float* __restrict__ mlp_w, char* __restrict__ mlp_q,
                  const float* __restrict__ p_iva, const float* __restrict__ p_muiva,
                  const float* __restrict__ m_iva, const float* __restrict__ m_muiva,
                  float* __restrict__ s_all)
{
  __shared__ alignas(16) float efs[8192];
  __shared__ float wmax[4];
  const int bx = blockIdx.x;
  const int tid = threadIdx.x;
  const int wv = tid >> 6, lane = tid & 63;
  float4* eflds = (float4*)(efs + wv * 2048);

  if (bx < 512) {
    const int row = bx * 4 + wv;
    const float4* src = (const float4*)(proj_w + (size_t)row * 2048);
    const float4* A4 = (const float4*)p_iva;
    const float4* MUIVA4 = (const float4*)p_muiva;
    char4* dst = (char4*)(proj_q + (size_t)row * 2048);
    float m = 0.f;
#pragma unroll
    for (int it = 0; it < 8; ++it) {
      int i = it * 64 + lane;
      float4 v = src[i];
      float4 a = A4[i], mv = MUIVA4[i];
      float4 e;
      e.x = fmaf(v.x, a.x, -mv.x);
      e.y = fmaf(v.y, a.y, -mv.y);
      e.z = fmaf(v.z, a.z, -mv.z);
      e.w = fmaf(v.w, a.w, -mv.w);
      eflds[i] = e;
      m = fmaxf(m, fmaxf(fmaxf(fabsf(e.x), fabsf(e.y)), fmaxf(fabsf(e.z), fabsf(e.w))));
    }
    for (int mask = 32; mask; mask >>= 1) m = fmaxf(m, __shfl_xor(m, mask));
    if (lane == 0) s_all[11264 + row] = m * (1.f / 127.f);
    const float r = (m > 0.f) ? 127.f / m : 0.f;
#pragma unroll
    for (int it = 0; it < 8; ++it) {
      int i = it * 64 + lane;
      float4 e = eflds[i];
      char4 q;
      q.x = q8(e.x, r); q.y = q8(e.y, r);
      q.z = q8(e.z, r); q.w = q8(e.w, r);
      dst[i] = q;
    }
  } else {
    const int row = bx - 512;
    const float4* src = (const float4*)(mlp_w + (size_t)row * 8192);
    const float4* A4 = (const float4*)m_iva;
    const float4* MUIVA4 = (const float4*)m_muiva;
    char4* dst = (char4*)(mlp_q + (size_t)row * 8192);
    float m = 0.f;
#pragma unroll
    for (int it = 0; it < 8; ++it) {
      int li = it * 64 + lane;
      int i = wv * 512 + li;
      float4 v = src[i];
      float4 a = A4[i], mv = MUIVA4[i];
      float4 e;
      e.x = fmaf(v.x, a.x, -mv.x);
      e.y = fmaf(v.y, a.y, -mv.y);
      e.z = fmaf(v.z, a.z, -mv.z);
      e.w = fmaf(v.w, a.w, -mv.w);
      eflds[li] = e;
      m = fmaxf(m, fmaxf(fmaxf(fabsf(e.x), fabsf(e.y)), fmaxf(fabsf(e.z), fabsf(e.w))));
    }
    for (int mask = 32; mask; mask >>= 1) m = fmaxf(m, __shfl_xor(m, mask));
    if (lane == 0) wmax[wv] = m;
    __syncthreads();
    m = fmaxf(fmaxf(wmax[0], wmax[1]), fmaxf(wmax[2], wmax[3]));
    if (tid == 0) s_all[13312 + row] = m * (1.f / 127.f);
    const float r = (m > 0.f) ? 127.f / m : 0.f;
#pragma unroll
    for (int it = 0; it < 8; ++it) {
      int li = it * 64 + lane;
      int i = wv * 512 + li;
      float4 e = eflds[li];
      char4 q;
      q.x = q8(e.x, r); q.y = q8(e.y, r);
      q.z = q8(e.z, r); q.w = q8(e.w, r);
      dst[i] = q;
    }
  }
}

// outputs iva = (scale/norm)*alpha, muiva = mu*iva
__global__ void stats2_all(const float* __restrict__ ps, const float* __restrict__ ps2,
                           float* __restrict__ p_iva, float* __restrict__ p_muiva,
                           const float* __restrict__ pscale, const float* __restrict__ outA,
                           const float* __restrict__ ms, const float* __restrict__ ms2,
                           float* __restrict__ m_iva, float* __restrict__ m_muiva,
                           const float* __restrict__ mscale, const float* __restrict__ a2A)
{
  const int bx = blockIdx.x;
  const float* S; const float* S2; float* iva; float* muiva;
  const float* sc; const float* A; int cols, j;
  if (bx < 8) { S = ps; S2 = ps2; iva = p_iva; muiva = p_muiva; sc = pscale; A = outA; cols = 2048; j = bx * 256 + threadIdx.x; }
  else        { S = ms; S2 = ms2; iva = m_iva; muiva = m_muiva; sc = mscale; A = a2A;  cols = 8192; j = (bx - 8) * 256 + threadIdx.x; }
  float s = 0.f, s2 = 0.f;
  for (int c = 0; c < 16; ++c) { s += S[c * cols + j]; s2 += S2[c * cols + j]; }
  float m = s * (1.f / 2048.f);
  float var = s2 - s * m;
  float nn = sqrtf(fmaxf(var, 0.f));
  nn = fmaxf(nn, 1e-12f);
  float iv = (sc[0] / nn) * A[j];
  iva[j] = iv;
  muiva[j] = m * iv;
}

extern "C" void kernel_launch(void* const* d_in, const int* in_sizes, int n_in,
                              void* d_out, int out_size, void* d_ws, size_t ws_size,
                              hipStream_t stream) {
  const float* x          = (const float*)d_in[0];
  const float* cosT       = (const float*)d_in[1];
  const float* sinT       = (const float*)d_in[2];
  const float* attn_w     = (const float*)d_in[3];
  const float* proj_w     = (const float*)d_in[4];
  const float* proj_scale = (const float*)d_in[5];
  const float* fc_w       = (const float*)d_in[6];
  const float* mlp_proj_w = (const float*)d_in[7];
  const float* mlp_scale  = (const float*)d_in[8];
  const float* in_alpha   = (const float*)d_in[9];
  const float* in_beta    = (const float*)d_in[10];
  const float* q_alpha    = (const float*)d_in[11];
  const float* q_beta     = (const float*)d_in[12];
  const float* k_alpha    = (const float*)d_in[13];
  const float* k_beta     = (const float*)d_in[14];
  const float* out_alpha  = (const float*)d_in[15];
  const float* out_beta   = (const float*)d_in[16];
  const float* act1_alpha = (const float*)d_in[17];
  const float* act1_beta  = (const float*)d_in[18];
  const float* act2_alpha = (const float*)d_in[19];
  const float* act2_beta  = (const float*)d_in[20];

  char* cur = (char*)d_ws;
  auto alloc = [&](size_t b) { void* p = cur; cur += (b + 255) & ~(size_t)255; return p; };

  // i8 weights & activations
  char* attn_q = (char*)alloc((size_t)3072 * 2048);
  char* fc_q   = (char*)alloc((size_t)8192 * 2048);
  char* proj_q = (char*)alloc((size_t)2048 * 2048);
  char* mlp_q  = (char*)alloc((size_t)2048 * 8192);
  char* h_in   = (char*)alloc((size_t)2048 * 2048);
  char* h_y    = (char*)alloc((size_t)2048 * 2048);
  char* h2     = (char*)alloc((size_t)2048 * 2048);
  char* h3     = (char*)alloc((size_t)2048 * 8192);
  // bf16 attention operands
  ushort* qbuf  = (ushort*)alloc((size_t)HQ * TT * DD * 2);
  ushort* kbuf  = (ushort*)alloc((size_t)GG * TT * DD * 2);
  ushort* vtbuf = (ushort*)alloc((size_t)GG * DD * TT * 2);
  // f32
  float* x2 = (float*)alloc((size_t)2048 * 2048 * 4);
  // bf16 split-K partial planes
  ushort* qkv_parts  = (ushort*)alloc((size_t)2 * 2048 * 3072 * 2);
  ushort* proj_parts = (ushort*)alloc((size_t)4 * 2048 * 2048 * 2);
  ushort* mlp_parts  = (ushort*)alloc((size_t)4 * 2048 * 2048 * 2);
  // stats + scales
  float* pp_s  = (float*)alloc(16 * 2048 * 4);
  float* pp_s2 = (float*)alloc(16 * 2048 * 4);
  float* mp_s  = (float*)alloc(16 * 8192 * 4);
  float* mp_s2 = (float*)alloc(16 * 8192 * 4);
  float* p_iva   = (float*)alloc(2048 * 4);
  float* p_muiva = (float*)alloc(2048 * 4);
  float* m_iva   = (float*)alloc(8192 * 4);
  float* m_muiva = (float*)alloc(8192 * 4);
  float* s_all = (float*)alloc(15360 * 4);

  const size_t PLANE_QKV = (size_t)2048 * 3072;
  const size_t PLANE     = (size_t)2048 * 2048;

  float* s_attn = s_all;
  float* s_fc   = s_all + 3072;
  float* s_proj = s_all + 11264;
  float* s_mlp  = s_all + 13312;

  // prep: prep1 (attn/fc quant + h_in + stats1) -> stats2 -> prep2 (proj/mlp quant)
  prep1_kernel<<<3968, 256, 0, stream>>>(attn_w, attn_q, fc_w, fc_q,
                                         in_alpha, act1_alpha, s_all,
                                         x, in_beta, h_in,
                                         proj_w, mlp_proj_w, pp_s, pp_s2, mp_s, mp_s2);
  stats2_all<<<40, 256, 0, stream>>>(pp_s, pp_s2, p_iva, p_muiva, proj_scale, out_alpha,
                                     mp_s, mp_s2, m_iva, m_muiva, mlp_scale, act2_alpha);
  prep2_kernel<<<2560, 256, 0, stream>>>(proj_w, proj_q, mlp_proj_w, mlp_q,
                                         p_iva, p_muiva, m_iva, m_muiva, s_all);

  // qkv = h_in @ attn_q^T * s_attn  (split-K x2, bf16 partials; sum fused into rope)
  gemm_i8<3><<<dim3(3072 / 256, 2048 / 256, 2), 512, 0, stream>>>(
      h_in, attn_q, qkv_parts, s_attn, nullptr, 2048, 3072, 2048, 1024);

  // rope + hv -> q,k bf16 ; transpose v  (job-split grid)
  rope_hv_kernel<<<dim3(TT / 64, GG, 6), 256, 0, stream>>>(
      qkv_parts, qkv_parts + PLANE_QKV, cosT, sinT,
      q_alpha, q_beta, k_alpha, k_beta, qbuf, kbuf, vtbuf);

  // fused causal relu attention v4 -> h_y i8 {0,1}
  attn_kernel<<<dim3(TT / 64, HQ), 256, 0, stream>>>(qbuf, kbuf, vtbuf, h_y, out_beta);

  // x2 = x + h_y @ proj_q^T * s_proj (split-K x4), fused h2 = (x2 - act1_beta > 0)
  gemm_i8<3><<<dim3(2048 / 256, 2048 / 256, 4), 512, 0, stream>>>(
      h_y, proj_q, proj_parts, s_proj, nullptr, 2048, 2048, 2048, 512);
  reduce_kernel<4, 1><<<2048, 256, 0, stream>>>(
      proj_parts, proj_parts + PLANE, proj_parts + 2 * PLANE, proj_parts + 3 * PLANE,
      x, x2, h2, act1_beta, 2048 * 2048 / 4, 2048);

  // h3 = (h2 @ fc_q^T * s_fc - act2_beta > 0)  i8
  gemm_i8<1><<<dim3(8192 / 256, 2048 / 256, 1), 512, 0, stream>>>(
      h2, fc_q, h3, s_fc, act2_beta, 2048, 8192, 2048, 2048);

  // out = x2 + h3 @ mlp_q^T * s_mlp (split-K x4)
  gemm_i8<3><<<dim3(8, 8, 4), 512, 0, stream>>>(
      h3, mlp_q, mlp_parts, s_mlp, nullptr, 2048, 2048, 8192, 2048);
  reduce_kernel<4, 2><<<2048, 256, 0, stream>>>(
      mlp_parts, mlp_parts + PLANE, mlp_parts + 2 * PLANE, mlp_parts + 3 * PLANE,
      x2, (float*)d_out, nullptr, nullptr, 2048 * 2048 / 4, 1);
}

// Round 19
// 254.634 us; speedup vs baseline: 1.0461x; 1.0354x over previous
//
#include <hip/hip_runtime.h>

typedef __attribute__((ext_vector_type(8))) short short8;
typedef __attribute__((ext_vector_type(4))) float f32x4;
typedef __attribute__((ext_vector_type(4))) int i32x4;

constexpr int TT = 2048, CC = 2048, HQ = 16, GG = 4, DD = 128, IC = 8192;

__device__ __forceinline__ ushort f2b(float f) {
  union { float f; unsigned u; } v; v.f = f;
  unsigned r = v.u + 0x7fffu + ((v.u >> 16) & 1u);
  return (ushort)(r >> 16);
}
__device__ __forceinline__ float b2f(ushort u) {
  union { unsigned u; float f; } v; v.u = ((unsigned)u) << 16; return v.f;
}
__device__ __forceinline__ char q8(float eff, float r) {
  float q = rintf(eff * r);
  q = fminf(fmaxf(q, -127.f), 127.f);
  return (char)(int)q;
}
__device__ __forceinline__ unsigned cvt_pk_bf16(float a, float b) {
  unsigned r;
  asm("v_cvt_pk_bf16_f32 %0, %1, %2" : "=v"(r) : "v"(a), "v"(b));
  return r;
}

__device__ __forceinline__ void gload16(const void* g, void* l) {
  __builtin_amdgcn_global_load_lds(
      (const __attribute__((address_space(1))) void*)g,
      (__attribute__((address_space(3))) void*)l, 16, 0, 0);
}

#define BAR()    __builtin_amdgcn_s_barrier()
#define PRIO1()  __builtin_amdgcn_s_setprio(1)
#define PRIO0()  __builtin_amdgcn_s_setprio(0)

// ====== 256x256 i8 GEMM, R7 pipeline clone: C[M,N] = (A{0,1} @ Bq^T) * s[n] ======
template<int EPI>
__global__ __launch_bounds__(512, 2)
void gemm_i8(const char* __restrict__ A, const char* __restrict__ B,
             void* __restrict__ C0, const float* __restrict__ s,
             const float* __restrict__ beta, int M, int N, int K, int kc)
{
  __shared__ alignas(16) char lds[131072];
  const int tid = threadIdx.x;
  const int l = tid & 63, w = tid >> 6;
  const int fl = l & 15, fh = l >> 4;
  const int wrm = w >> 2, wcn = w & 3;
  const int m0 = blockIdx.y * 256, n0 = blockIdx.x * 256;
  const int kBeg = blockIdx.z * kc;
  const int kEnd = (kBeg + kc < K) ? kBeg + kc : K;
  const int nt = (kEnd - kBeg) >> 7;

  i32x4 acc[8][4] = {};

  const int srow = tid >> 3;
  const int scol = ((tid & 7) ^ (srow & 7)) * 16;
  const char* Ag = A + (size_t)(m0 + srow) * K + kBeg + scol;
  const char* Bg = B + (size_t)(n0 + srow) * K + kBeg + scol;

  auto stage_half = [&](int tile, int h) {
    const char* base = (h < 2) ? Ag : Bg;
    const int half = h & 1;
    const char* g = base + (size_t)(half * 128) * K + tile * 128;
    char* d = lds + (tile & 1) * 65536 + ((h < 2) ? 0 : 32768) + half * 16384 + tid * 16;
    gload16(g, d);
    gload16(g + (size_t)64 * K, d + 8192);
  };

  auto readA = [&](i32x4 (&dst)[4][2], int buf, int mofs) {
#pragma unroll
    for (int mf = 0; mf < 4; ++mf)
#pragma unroll
      for (int ks = 0; ks < 2; ++ks) {
        int row = wrm * 128 + (mofs + mf) * 16 + fl;
        dst[mf][ks] = *(const i32x4*)(lds + buf * 65536 + row * 128 +
                                      (((ks * 4 + fh) ^ (row & 7)) * 16));
      }
  };
  auto readB = [&](i32x4 (&dst)[2][2], int buf, int nofs) {
#pragma unroll
    for (int nf = 0; nf < 2; ++nf)
#pragma unroll
      for (int ks = 0; ks < 2; ++ks) {
        int row = wcn * 64 + (nofs + nf) * 16 + fl;
        dst[nf][ks] = *(const i32x4*)(lds + buf * 65536 + 32768 + row * 128 +
                                      (((ks * 4 + fh) ^ (row & 7)) * 16));
      }
  };
  auto mmQ = [&](i32x4 (&a)[4][2], i32x4 (&b)[2][2], int mo, int no) {
    PRIO1();
#pragma unroll
    for (int mf = 0; mf < 4; ++mf)
#pragma unroll
      for (int nf = 0; nf < 2; ++nf)
#pragma unroll
        for (int ks = 0; ks < 2; ++ks)
          acc[mo + mf][no + nf] = __builtin_amdgcn_mfma_i32_16x16x64_i8(
              a[mf][ks], b[nf][ks], acc[mo + mf][no + nf], 0, 0, 0);
    PRIO0();
  };

  stage_half(0, 0); stage_half(0, 1); stage_half(0, 2); stage_half(0, 3);
  if (nt > 1) {
    stage_half(1, 2); stage_half(1, 3);
    asm volatile("s_waitcnt vmcnt(4)" ::: "memory");
  } else {
    asm volatile("s_waitcnt vmcnt(0)" ::: "memory");
  }
  BAR();

  for (int t = 0; t < nt; ++t) {
    const int buf = t & 1;
    i32x4 A0[4][2], A1[4][2], B0[2][2], B1[2][2];

    readA(A0, buf, 0);
    readB(B0, buf, 0);
    if (t + 1 < nt) stage_half(t + 1, 0);
    BAR();
    mmQ(A0, B0, 0, 0);

    readB(B1, buf, 2);
    if (t + 1 < nt) stage_half(t + 1, 1);
    BAR();
    mmQ(A0, B1, 0, 2);

    readA(A1, buf, 4);
    BAR();
    mmQ(A1, B0, 4, 0);

    if (t + 2 < nt) { stage_half(t + 2, 2); stage_half(t + 2, 3); }
    if (t <= nt - 3) asm volatile("s_waitcnt vmcnt(4)" ::: "memory");
    else             asm volatile("s_waitcnt vmcnt(0)" ::: "memory");
    BAR();
    mmQ(A1, B1, 4, 2);
  }

  const int orow0 = m0 + wrm * 128 + fh * 4;
  const int ocol0 = n0 + wcn * 64 + fl;
#pragma unroll
  for (int mf = 0; mf < 8; ++mf) {
#pragma unroll
    for (int nf = 0; nf < 4; ++nf) {
      const int c = ocol0 + nf * 16;
      const float sc = s[c];
#pragma unroll
      for (int j = 0; j < 4; ++j) {
        const int r = orow0 + mf * 16 + j;
        const size_t o = (size_t)r * N + c;
        float v = (float)acc[mf][nf][j] * sc;
        if constexpr (EPI == 1) {
          ((char*)C0)[o] = (v - beta[c] > 0.f) ? (char)1 : (char)0;
        } else {
          ((ushort*)C0 + (size_t)blockIdx.z * M * N)[o] = f2b(v);
        }
      }
    }
  }
}

// ---------------- split-K reduce: bf16 partial planes ----------------
template<int NS, int MODE>
__global__ void reduce_kernel(const ushort* p0, const ushort* p1, const ushort* p2, const ushort* p3,
                              const float* resid, float* outf, char* outb,
                              const float* beta, int n4, int cols)
{
  const ushort* ps[4] = {p0, p1, p2, p3};
  for (int i = blockIdx.x * blockDim.x + threadIdx.x; i < n4; i += gridDim.x * blockDim.x) {
    float4 s = ((const float4*)resid)[i];
#pragma unroll
    for (int z = 0; z < NS; ++z) {
      ushort4 q = ((const ushort4*)ps[z])[i];
      s.x += b2f(q.x); s.y += b2f(q.y); s.z += b2f(q.z); s.w += b2f(q.w);
    }
    ((float4*)outf)[i] = s;
    if constexpr (MODE == 1) {
      int c = (i * 4) & (cols - 1);
      char4 r;
      r.x = (s.x - beta[c] > 0.f) ? 1 : 0;
      r.y = (s.y - beta[c + 1] > 0.f) ? 1 : 0;
      r.z = (s.z - beta[c + 2] > 0.f) ? 1 : 0;
      r.w = (s.w - beta[c + 3] > 0.f) ? 1 : 0;
      ((char4*)outb)[i] = r;
    }
  }
}

// ---- attn v5: split-s x2 (relu-attn O is a pure sum -> exact additive partials) ----
// Block z handles s-tiles s0 = z*64, z*64+128, ... ; partial O -> bf16 plane opart[z].
__global__ __launch_bounds__(256, 4)
void attn_kernel(const ushort* __restrict__ qb, const ushort* __restrict__ kb,
                 const ushort* __restrict__ vt, ushort* __restrict__ opart)
{
  __shared__ alignas(16) ushort Ks[64 * 128];
  __shared__ alignas(16) ushort Vs[128 * 64];
  __shared__ alignas(16) ushort Ps[64 * 64];
  const int bx = blockIdx.x;
  const int h = blockIdx.y;
  const int z = blockIdx.z;
  const int qi = (h & 8) ? bx : (31 - bx);
  const int g = h >> 2;
  const int q0 = qi * 64;
  const int tid = threadIdx.x;
  const int w = tid >> 6, l = tid & 63;
  const int fl = l & 15, fh = l >> 4;

  auto stageK = [&](int s0t) {
#pragma unroll
    for (int i = 0; i < 4; ++i) {
      int row = w * 16 + i * 4 + (l >> 4);
      int c16 = (l & 15) ^ (row & 7);
      gload16(kb + (size_t)g * TT * DD + (size_t)(s0t + row) * DD + c16 * 8,
              (char*)Ks + (w << 12) + (i << 10) + (l << 4));
    }
  };
  auto stageV = [&](int s0t) {
#pragma unroll
    for (int i = 0; i < 4; ++i) {
      int d = w * 32 + i * 8 + (l >> 3);
      int c16 = (l & 7) ^ (d & 7);
      gload16(vt + (size_t)g * DD * TT + (size_t)d * TT + s0t + c16 * 8,
              (char*)Vs + (w << 12) + (i << 10) + (l << 4));
    }
  };

  short8 qf[4];
  {
    const ushort* qp = qb + (size_t)h * TT * DD + (size_t)(q0 + w * 16 + fl) * DD + fh * 8;
#pragma unroll
    for (int ks = 0; ks < 4; ++ks) qf[ks] = *(const short8*)(qp + ks * 32);
  }

  const int prow = w * 16 + fl;
  const int qg = q0 + prow;
  f32x4 oacc[8] = {};

  for (int s0 = z * 64; s0 <= q0; s0 += 128) {
    stageK(s0); stageV(s0);
    asm volatile("s_waitcnt vmcnt(0)" ::: "memory");
    BAR();

    f32x4 sacc[4] = {};
#pragma unroll
    for (int ks = 0; ks < 4; ++ks) {
#pragma unroll
      for (int n = 0; n < 4; ++n) {
        int krow = n * 16 + fl;
        int slotB = (ks * 4 + fh) ^ (krow & 7);
        short8 kf = *(const short8*)((char*)Ks + krow * 256 + slotB * 16);
        sacc[n] = __builtin_amdgcn_mfma_f32_16x16x32_bf16(kf, qf[ks], sacc[n], 0, 0, 0);
      }
    }

    const bool diag = (s0 == q0);
#pragma unroll
    for (int n = 0; n < 4; ++n) {
      float p[4];
#pragma unroll
      for (int j = 0; j < 4; ++j) {
        float v = sacc[n][j] * 0.0078125f;
        v = fmaxf(v, 0.f);
        if (diag) {
          int sg = s0 + n * 16 + fh * 4 + j;
          if (sg > qg) v = 0.f;
        }
        p[j] = v;
      }
      unsigned lo = cvt_pk_bf16(p[0], p[1]);
      unsigned hi = cvt_pk_bf16(p[2], p[3]);
      int slot = ((n * 2 + (fh >> 1)) ^ (prow & 7));
      char* addr = (char*)Ps + prow * 128 + slot * 16 + ((fh & 1) << 3);
      uint2 val; val.x = lo; val.y = hi;
      *(uint2*)addr = val;
    }

#pragma unroll
    for (int ks = 0; ks < 2; ++ks) {
      int slotA = (ks * 4 + fh) ^ (prow & 7);
      short8 pa = *(const short8*)((char*)Ps + prow * 128 + slotA * 16);
#pragma unroll
      for (int n = 0; n < 8; ++n) {
        int vrow = n * 16 + fl;
        int slotB = (ks * 4 + fh) ^ (vrow & 7);
        short8 vb = *(const short8*)((char*)Vs + vrow * 128 + slotB * 16);
        oacc[n] = __builtin_amdgcn_mfma_f32_16x16x32_bf16(pa, vb, oacc[n], 0, 0, 0);
      }
    }

    BAR();
  }

  // partial O -> bf16 plane z (written unconditionally, including zero partials)
  ushort* op = opart + (size_t)z * TT * CC;
#pragma unroll
  for (int n = 0; n < 8; ++n) {
    const int c = h * DD + n * 16 + fl;
#pragma unroll
    for (int j = 0; j < 4; ++j) {
      const int tq = q0 + w * 16 + fh * 4 + j;
      op[(size_t)tq * CC + c] = f2b(oacc[n][j]);
    }
  }
}

// ---- merge split-s partials: h_y = (p0 + p1 - out_beta > 0) i8 ----
__global__ void merge_hy(const ushort* __restrict__ p0, const ushort* __restrict__ p1,
                         const float* __restrict__ obeta, char* __restrict__ hy, int n4)
{
  for (int i = blockIdx.x * blockDim.x + threadIdx.x; i < n4; i += gridDim.x * blockDim.x) {
    ushort4 a = ((const ushort4*)p0)[i];
    ushort4 b = ((const ushort4*)p1)[i];
    int c = (i * 4) & (CC - 1);
    char4 r;
    r.x = (b2f(a.x) + b2f(b.x) - obeta[c] > 0.f) ? 1 : 0;
    r.y = (b2f(a.y) + b2f(b.y) - obeta[c + 1] > 0.f) ? 1 : 0;
    r.z = (b2f(a.z) + b2f(b.z) - obeta[c + 2] > 0.f) ? 1 : 0;
    r.w = (b2f(a.w) + b2f(b.w) - obeta[c + 3] > 0.f) ? 1 : 0;
    ((char4*)hy)[i] = r;
  }
}

// ---------- rope + hv on q/k, transpose+cast v ; split across blockIdx.z ----------
__global__ __launch_bounds__(256)
void rope_hv_kernel(const ushort* __restrict__ qp0, const ushort* __restrict__ qp1,
                    const float* __restrict__ cs, const float* __restrict__ sn,
                    const float* __restrict__ qalpha, const float* __restrict__ qbeta,
                    const float* __restrict__ kalpha, const float* __restrict__ kbeta,
                    ushort* __restrict__ qb, ushort* __restrict__ kb,
                    ushort* __restrict__ vt)
{
  __shared__ ushort Vsh[64][129];
  const int t0 = blockIdx.x * 64, g = blockIdx.y, job = blockIdx.z;
  const int tid = threadIdx.x;
  if (job < 5) {
    const int hh = job;
    const float* alpha = (hh < 4) ? qalpha : kalpha;
    const float* beta = (hh < 4) ? qbeta : kbeta;
    const int hoff = (hh < 4) ? hh * 128 : 512;
    for (int it = 0; it < 16; ++it) {
      int idx = it * 256 + tid;
      int tr = idx >> 6, dd = idx & 63;
      size_t base = (size_t)(t0 + tr) * 3072 + g * 768 + hoff;
      float x1 = b2f(qp0[base + dd]) + b2f(qp1[base + dd]);
      float x2 = b2f(qp0[base + 64 + dd]) + b2f(qp1[base + 64 + dd]);
      float c = cs[(size_t)(t0 + tr) * 64 + dd];
      float s = sn[(size_t)(t0 + tr) * 64 + dd];
      float o1 = x1 * c - x2 * s, o2 = x1 * s + x2 * c;
      ushort b1 = (o1 - beta[dd] > 0.f) ? f2b(alpha[dd]) : (ushort)0;
      ushort b2 = (o2 - beta[64 + dd] > 0.f) ? f2b(alpha[64 + dd]) : (ushort)0;
      if (hh < 4) {
        size_t o = ((size_t)(g * 4 + hh) * TT + t0 + tr) * DD;
        qb[o + dd] = b1;
        qb[o + 64 + dd] = b2;
      } else {
        size_t o = ((size_t)g * TT + t0 + tr) * DD;
        kb[o + dd] = b1;
        kb[o + 64 + dd] = b2;
      }
    }
  } else {
    for (int it = 0; it < 32; ++it) {
      int idx = it * 256 + tid;
      int tr = idx >> 7, d = idx & 127;
      size_t src = (size_t)(t0 + tr) * 3072 + g * 768 + 640 + d;
      Vsh[tr][d] = f2b(b2f(qp0[src]) + b2f(qp1[src]));
    }
    __syncthreads();
    for (int it = 0; it < 32; ++it) {
      int idx = it * 256 + tid;
      int d = idx >> 6, tl = idx & 63;
      vt[((size_t)g * DD + d) * TT + t0 + tl] = Vsh[tl][d];
    }
  }
}

// ======== prep1: attn-quant + fc-quant + h_in + stats1 column sums, ONE dispatch ========
__global__ __launch_bounds__(256, 4)
void prep1_kernel(const float* __restrict__ attn_w, char* __restrict__ attn_q,
                  const float* __restrict__ fc_w, char* __restrict__ fc_q,
                  const float* __restrict__ inA, const float* __restrict__ a1A,
                  float* __restrict__ s_all,
                  const float* __restrict__ x, const float* __restrict__ ib,
                  char* __restrict__ h_in,
                  const float* __restrict__ pw, const float* __restrict__ mw,
                  float* __restrict__ ps, float* __restrict__ ps2,
                  float* __restrict__ ms, float* __restrict__ ms2)
{
  __shared__ alignas(16) float efs[8192];
  const int bx = blockIdx.x;
  const int tid = threadIdx.x;
  const int wv = tid >> 6, lane = tid & 63;
  float4* eflds = (float4*)(efs + wv * 2048);

  if (bx < 2816) {
    const float* W; char* Q; const float4* A4;
    int row, sofs;
    if (bx < 768) { W = attn_w; Q = attn_q; A4 = (const float4*)inA; row = bx * 4 + wv;         sofs = 0; }
    else          { W = fc_w;   Q = fc_q;   A4 = (const float4*)a1A; row = (bx - 768) * 4 + wv; sofs = 3072; }
    const float4* src = (const float4*)(W + (size_t)row * 2048);
    char4* dst = (char4*)(Q + (size_t)row * 2048);
    float m = 0.f;
#pragma unroll
    for (int it = 0; it < 8; ++it) {
      int i = it * 64 + lane;
      float4 v = src[i];
      float4 a = A4[i];
      float4 e;
      e.x = v.x * a.x; e.y = v.y * a.y; e.z = v.z * a.z; e.w = v.w * a.w;
      eflds[i] = e;
      m = fmaxf(m, fmaxf(fmaxf(fabsf(e.x), fabsf(e.y)), fmaxf(fabsf(e.z), fabsf(e.w))));
    }
    for (int mask = 32; mask; mask >>= 1) m = fmaxf(m, __shfl_xor(m, mask));
    if (lane == 0) s_all[sofs + row] = m * (1.f / 127.f);
    const float r = (m > 0.f) ? 127.f / m : 0.f;
#pragma unroll
    for (int it = 0; it < 8; ++it) {
      int i = it * 64 + lane;
      float4 e = eflds[i];
      char4 q;
      q.x = q8(e.x, r); q.y = q8(e.y, r);
      q.z = q8(e.z, r); q.w = q8(e.w, r);
      dst[i] = q;
    }
  } else if (bx < 3328) {
    const int blk = bx - 2816;
    const int stride = 512 * 256;
    const float4* ib4 = (const float4*)ib;
    for (int i = blk * 256 + tid; i < 2048 * 2048 / 4; i += stride) {
      float4 v = ((const float4*)x)[i];
      float4 b = ib4[i & 511];
      char4 q;
      q.x = (v.x - b.x > 0.f) ? 1 : 0;
      q.y = (v.y - b.y > 0.f) ? 1 : 0;
      q.z = (v.z - b.z > 0.f) ? 1 : 0;
      q.w = (v.w - b.w > 0.f) ? 1 : 0;
      ((char4*)h_in)[i] = q;
    }
  } else {
    const int jb = bx - 3328;
    const int sb = jb % 40;
    const int chunk = jb / 40;
    const float* W;
    float* os; float* os2; int cols, j;
    if (sb < 8) { W = pw; os = ps; os2 = ps2; cols = 2048; j = sb * 256 + tid; }
    else        { W = mw; os = ms; os2 = ms2; cols = 8192; j = (sb - 8) * 256 + tid; }
    const float* p = W + (size_t)chunk * 128 * cols + j;
    float s = 0.f, s2 = 0.f;
    for (int i = 0; i < 128; ++i) { float v = p[(size_t)i * cols]; s += v; s2 += v * v; }
    os[chunk * cols + j] = s;
    os2[chunk * cols + j] = s2;
  }
}

// ======== prep2: proj + mlp quant (stats-dependent; reads are L3-hot) ========
__global__ __launch_bounds__(256, 4)
void prep2_kernel(const float* __restrict__ proj_w, char* __restrict__ proj_q,
                  const float* __restrict__ mlp_w, char* __restrict__ mlp_q,
                  const float* __restrict__ p_iva, const float* __restrict__ p_muiva,
                  const float* __restrict__ m_iva, const float* __restrict__ m_muiva,
                  float* __restrict__ s_all)
{
  __shared__ alignas(16) float efs[8192];
  __shared__ float wmax[4];
  const int bx = blockIdx.x;
  const int tid = threadIdx.x;
  const int wv = tid >> 6, lane = tid & 63;
  float4* eflds = (float4*)(efs + wv * 2048);

  if (bx < 512) {
    const int row = bx * 4 + wv;
    const float4* src = (const float4*)(proj_w + (size_t)row * 2048);
    const float4* A4 = (const float4*)p_iva;
    const float4* MUIVA4 = (const float4*)p_muiva;
    char4* dst = (char4*)(proj_q + (size_t)row * 2048);
    float m = 0.f;
#pragma unroll
    for (int it = 0; it < 8; ++it) {
      int i = it * 64 + lane;
      float4 v = src[i];
      float4 a = A4[i], mv = MUIVA4[i];
      float4 e;
      e.x = fmaf(v.x, a.x, -mv.x);
      e.y = fmaf(v.y, a.y, -mv.y);
      e.z = fmaf(v.z, a.z, -mv.z);
      e.w = fmaf(v.w, a.w, -mv.w);
      eflds[i] = e;
      m = fmaxf(m, fmaxf(fmaxf(fabsf(e.x), fabsf(e.y)), fmaxf(fabsf(e.z), fabsf(e.w))));
    }
    for (int mask = 32; mask; mask >>= 1) m = fmaxf(m, __shfl_xor(m, mask));
    if (lane == 0) s_all[11264 + row] = m * (1.f / 127.f);
    const float r = (m > 0.f) ? 127.f / m : 0.f;
#pragma unroll
    for (int it = 0; it < 8; ++it) {
      int i = it * 64 + lane;
      float4 e = eflds[i];
      char4 q;
      q.x = q8(e.x, r); q.y = q8(e.y, r);
      q.z = q8(e.z, r); q.w = q8(e.w, r);
      dst[i] = q;
    }
  } else {
    const int row = bx - 512;
    const float4* src = (const float4*)(mlp_w + (size_t)row * 8192);
    const float4* A4 = (const float4*)m_iva;
    const float4* MUIVA4 = (const float4*)m_muiva;
    char4* dst = (char4*)(mlp_q + (size_t)row * 8192);
    float m = 0.f;
#pragma unroll
    for (int it = 0; it < 8; ++it) {
      int li = it * 64 + lane;
      int i = wv * 512 + li;
      float4 v = src[i];
      float4 a = A4[i], mv = MUIVA4[i];
      float4 e;
      e.x = fmaf(v.x, a.x, -mv.x);
      e.y = fmaf(v.y, a.y, -mv.y);
      e.z = fmaf(v.z, a.z, -mv.z);
      e.w = fmaf(v.w, a.w, -mv.w);
      eflds[li] = e;
      m = fmaxf(m, fmaxf(fmaxf(fabsf(e.x), fabsf(e.y)), fmaxf(fabsf(e.z), fabsf(e.w))));
    }
    for (int mask = 32; mask; mask >>= 1) m = fmaxf(m, __shfl_xor(m, mask));
    if (lane == 0) wmax[wv] = m;
    __syncthreads();
    m = fmaxf(fmaxf(wmax[0], wmax[1]), fmaxf(wmax[2], wmax[3]));
    if (tid == 0) s_all[13312 + row] = m * (1.f / 127.f);
    const float r = (m > 0.f) ? 127.f / m : 0.f;
#pragma unroll
    for (int it = 0; it < 8; ++it) {
      int li = it * 64 + lane;
      int i = wv * 512 + li;
      float4 e = eflds[li];
      char4 q;
      q.x = q8(e.x, r); q.y = q8(e.y, r);
      q.z = q8(e.z, r); q.w = q8(e.w, r);
      dst[i] = q;
    }
  }
}

// outputs iva = (scale/norm)*alpha, muiva = mu*iva
__global__ void stats2_all(const float* __restrict__ ps, const float* __restrict__ ps2,
                           float* __restrict__ p_iva, float* __restrict__ p_muiva,
                           const float* __restrict__ pscale, const float* __restrict__ outA,
                           const float* __restrict__ ms, const float* __restrict__ ms2,
                           float* __restrict__ m_iva, float* __restrict__ m_muiva,
                           const float* __restrict__ mscale, const float* __restrict__ a2A)
{
  const int bx = blockIdx.x;
  const float* S; const float* S2; float* iva; float* muiva;
  const float* sc; const float* A; int cols, j;
  if (bx < 8) { S = ps; S2 = ps2; iva = p_iva; muiva = p_muiva; sc = pscale; A = outA; cols = 2048; j = bx * 256 + threadIdx.x; }
  else        { S = ms; S2 = ms2; iva = m_iva; muiva = m_muiva; sc = mscale; A = a2A;  cols = 8192; j = (bx - 8) * 256 + threadIdx.x; }
  float s = 0.f, s2 = 0.f;
  for (int c = 0; c < 16; ++c) { s += S[c * cols + j]; s2 += S2[c * cols + j]; }
  float m = s * (1.f / 2048.f);
  float var = s2 - s * m;
  float nn = sqrtf(fmaxf(var, 0.f));
  nn = fmaxf(nn, 1e-12f);
  float iv = (sc[0] / nn) * A[j];
  iva[j] = iv;
  muiva[j] = m * iv;
}

extern "C" void kernel_launch(void* const* d_in, const int* in_sizes, int n_in,
                              void* d_out, int out_size, void* d_ws, size_t ws_size,
                              hipStream_t stream) {
  const float* x          = (const float*)d_in[0];
  const float* cosT       = (const float*)d_in[1];
  const float* sinT       = (const float*)d_in[2];
  const float* attn_w     = (const float*)d_in[3];
  const float* proj_w     = (const float*)d_in[4];
  const float* proj_scale = (const float*)d_in[5];
  const float* fc_w       = (const float*)d_in[6];
  const float* mlp_proj_w = (const float*)d_in[7];
  const float* mlp_scale  = (const float*)d_in[8];
  const float* in_alpha   = (const float*)d_in[9];
  const float* in_beta    = (const float*)d_in[10];
  const float* q_alpha    = (const float*)d_in[11];
  const float* q_beta     = (const float*)d_in[12];
  const float* k_alpha    = (const float*)d_in[13];
  const float* k_beta     = (const float*)d_in[14];
  const float* out_alpha  = (const float*)d_in[15];
  const float* out_beta   = (const float*)d_in[16];
  const float* act1_alpha = (const float*)d_in[17];
  const float* act1_beta  = (const float*)d_in[18];
  const float* act2_alpha = (const float*)d_in[19];
  const float* act2_beta  = (const float*)d_in[20];

  char* cur = (char*)d_ws;
  auto alloc = [&](size_t b) { void* p = cur; cur += (b + 255) & ~(size_t)255; return p; };

  // i8 weights & activations
  char* attn_q = (char*)alloc((size_t)3072 * 2048);
  char* fc_q   = (char*)alloc((size_t)8192 * 2048);
  char* proj_q = (char*)alloc((size_t)2048 * 2048);
  char* mlp_q  = (char*)alloc((size_t)2048 * 8192);
  char* h_in   = (char*)alloc((size_t)2048 * 2048);
  char* h_y    = (char*)alloc((size_t)2048 * 2048);
  char* h2     = (char*)alloc((size_t)2048 * 2048);
  char* h3     = (char*)alloc((size_t)2048 * 8192);
  // bf16 attention operands
  ushort* qbuf  = (ushort*)alloc((size_t)HQ * TT * DD * 2);
  ushort* kbuf  = (ushort*)alloc((size_t)GG * TT * DD * 2);
  ushort* vtbuf = (ushort*)alloc((size_t)GG * DD * TT * 2);
  // attn split-s bf16 partial O planes
  ushort* opart = (ushort*)alloc((size_t)2 * TT * CC * 2);
  // f32
  float* x2 = (float*)alloc((size_t)2048 * 2048 * 4);
  // bf16 split-K partial planes
  ushort* qkv_parts  = (ushort*)alloc((size_t)2 * 2048 * 3072 * 2);
  ushort* proj_parts = (ushort*)alloc((size_t)4 * 2048 * 2048 * 2);
  ushort* mlp_parts  = (ushort*)alloc((size_t)4 * 2048 * 2048 * 2);
  // stats + scales
  float* pp_s  = (float*)alloc(16 * 2048 * 4);
  float* pp_s2 = (float*)alloc(16 * 2048 * 4);
  float* mp_s  = (float*)alloc(16 * 8192 * 4);
  float* mp_s2 = (float*)alloc(16 * 8192 * 4);
  float* p_iva   = (float*)alloc(2048 * 4);
  float* p_muiva = (float*)alloc(2048 * 4);
  float* m_iva   = (float*)alloc(8192 * 4);
  float* m_muiva = (float*)alloc(8192 * 4);
  float* s_all = (float*)alloc(15360 * 4);

  const size_t PLANE_QKV = (size_t)2048 * 3072;
  const size_t PLANE     = (size_t)2048 * 2048;

  float* s_attn = s_all;
  float* s_fc   = s_all + 3072;
  float* s_proj = s_all + 11264;
  float* s_mlp  = s_all + 13312;

  // prep: prep1 (attn/fc quant + h_in + stats1) -> stats2 -> prep2 (proj/mlp quant)
  prep1_kernel<<<3968, 256, 0, stream>>>(attn_w, attn_q, fc_w, fc_q,
                                         in_alpha, act1_alpha, s_all,
                                         x, in_beta, h_in,
                                         proj_w, mlp_proj_w, pp_s, pp_s2, mp_s, mp_s2);
  stats2_all<<<40, 256, 0, stream>>>(pp_s, pp_s2, p_iva, p_muiva, proj_scale, out_alpha,
                                     mp_s, mp_s2, m_iva, m_muiva, mlp_scale, act2_alpha);
  prep2_kernel<<<2560, 256, 0, stream>>>(proj_w, proj_q, mlp_proj_w, mlp_q,
                                         p_iva, p_muiva, m_iva, m_muiva, s_all);

  // qkv = h_in @ attn_q^T * s_attn  (split-K x2, bf16 partials; sum fused into rope)
  gemm_i8<3><<<dim3(3072 / 256, 2048 / 256, 2), 512, 0, stream>>>(
      h_in, attn_q, qkv_parts, s_attn, nullptr, 2048, 3072, 2048, 1024);

  // rope + hv -> q,k bf16 ; transpose v  (job-split grid)
  rope_hv_kernel<<<dim3(TT / 64, GG, 6), 256, 0, stream>>>(
      qkv_parts, qkv_parts + PLANE_QKV, cosT, sinT,
      q_alpha, q_beta, k_alpha, k_beta, qbuf, kbuf, vtbuf);

  // fused causal relu attention v5 (split-s x2) -> bf16 partial O planes
  attn_kernel<<<dim3(TT / 64, HQ, 2), 256, 0, stream>>>(qbuf, kbuf, vtbuf, opart);
  // h_y = (p0 + p1 - out_beta > 0) i8
  merge_hy<<<2048, 256, 0, stream>>>(opart, opart + TT * CC, out_beta, h_y, TT * CC / 4);

  // x2 = x + h_y @ proj_q^T * s_proj (split-K x4), fused h2 = (x2 - act1_beta > 0)
  gemm_i8<3><<<dim3(2048 / 256, 2048 / 256, 4), 512, 0, stream>>>(
      h_y, proj_q, proj_parts, s_proj, nullptr, 2048, 2048, 2048, 512);
  reduce_kernel<4, 1><<<2048, 256, 0, stream>>>(
      proj_parts, proj_parts + PLANE, proj_parts + 2 * PLANE, proj_parts + 3 * PLANE,
      x, x2, h2, act1_beta, 2048 * 2048 / 4, 2048);

  // h3 = (h2 @ fc_q^T * s_fc - act2_beta > 0)  i8
  gemm_i8<1><<<dim3(8192 / 256, 2048 / 256, 1), 512, 0, stream>>>(
      h2, fc_q, h3, s_fc, act2_beta, 2048, 8192, 2048, 2048);

  // out = x2 + h3 @ mlp_q^T * s_mlp (split-K x4)
  gemm_i8<3><<<dim3(8, 8, 4), 512, 0, stream>>>(
      h3, mlp_q, mlp_parts, s_mlp, nullptr, 2048, 2048, 8192, 2048);
  reduce_kernel<4, 2><<<2048, 256, 0, stream>>>(
      mlp_parts, mlp_parts + PLANE, mlp_parts + 2 * PLANE, mlp_parts + 3 * PLANE,
      x2, (float*)d_out, nullptr, nullptr, 2048 * 2048 / 4, 1);
}